// Round 11
// baseline (272.381 us; speedup 1.0000x reference)
//
#include <hip/hip_runtime.h>

typedef _Float16 f16;
typedef _Float16 f16x4 __attribute__((ext_vector_type(4)));
typedef _Float16 f16x8 __attribute__((ext_vector_type(8)));
typedef float    f32x16 __attribute__((ext_vector_type(16)));

#define NB 32
#define TTOT 512
#define SSN 8256
#define PT 2064
#define EE 256
#define KCB 512

// ---------------- ws layout (bytes) ----------------
#define YB   ((size_t)NB*EE*PT*2)
#define LWB  ((size_t)EE*4096*2)
#define CBB  ((size_t)KCB*EE*2)
#define EBB  ((size_t)16384*EE*2)
#define OFF_Y0  ((size_t)0)
#define OFF_Y1  (YB)
#define OFF_LW0 (2*YB)
#define OFF_LW1 (2*YB + LWB)
#define OFF_CB0 (2*YB + 2*LWB)
#define OFF_CB1 (2*YB + 2*LWB + CBB)
#define OFF_HN  (2*YB + 2*LWB + 2*CBB)
#define OFF_E0  (OFF_HN + 4096)          // reused as f32 partial acc (16.78 MB = 2*EBB)
#define OFF_E1  (OFF_E0 + EBB)
#define WS_NEED (OFF_E1 + EBB)
#define PACC_BYTES ((size_t)16384*EE*4)

#define INV2048 4.8828125e-4f

struct h2 { f16 hi, lo; };
__device__ __forceinline__ h2 split2(float v) {
  h2 r;
  r.hi = (f16)v;
  r.lo = (f16)((v - (float)r.hi) * 2048.0f);
  return r;
}

__device__ __forceinline__ f16x8 ldsfrag(const f16* p) {
  union { f16x8 v8; f16x4 v4[2]; } u;
  u.v4[0] = *(const f16x4*)p;
  u.v4[1] = *(const f16x4*)(p + 4);
  return u.v8;
}

#define MFMA16(a,b,c) __builtin_amdgcn_mfma_f32_32x32x16_f16(a, b, c, 0, 0, 0)

// ================= k01: fused repack (k0) + conv (k1) =================
__global__ __launch_bounds__(256, 2)
void k01(const float* __restrict__ lin_w, const float* __restrict__ cbk,
         f16* __restrict__ lwp0, f16* __restrict__ lwp1,
         f16* __restrict__ cbp0, f16* __restrict__ cbp1, float* __restrict__ hn,
         const float* __restrict__ x, const float* __restrict__ cw,
         const float* __restrict__ cb, f16* __restrict__ y0, f16* __restrict__ y1)
{
  __shared__ float part[4][32];
  const int tid = threadIdx.x;
  const int bix = blockIdx.x;
  if (bix < 272) {
    const int bid = bix;
    if (bid < 256) {
      const int eo = bid, nb = eo >> 5, lo = eo & 31;
      const int ep = tid;
      const float* src = lin_w + (size_t)eo * 4096 + ep * 16;
      float f[16];
      *(float4*)(f + 0)  = ((const float4*)src)[0];
      *(float4*)(f + 4)  = ((const float4*)src)[1];
      *(float4*)(f + 8)  = ((const float4*)src)[2];
      *(float4*)(f + 12) = ((const float4*)src)[3];
      union { f16x8 v; f16 e[8]; } a0, a1, b0, b1;
#pragma unroll
      for (int i = 0; i < 8; ++i) {
        { h2 s = split2(f[i]);     a0.e[i] = s.hi; a1.e[i] = s.lo; }
        { h2 s = split2(f[i + 8]); b0.e[i] = s.hi; b1.e[i] = s.lo; }
      }
      const size_t base = ((size_t)nb * 16384 + (size_t)ep * 64 + lo) * 8;
      *(f16x8*)(lwp0 + base)       = a0.v;   // lane hi=0 slot
      *(f16x8*)(lwp0 + base + 256) = b0.v;   // lane hi=1 slot
      *(f16x8*)(lwp1 + base)       = a1.v;
      *(f16x8*)(lwp1 + base + 256) = b1.v;
    } else {
      const int jb = bid - 256;              // 0..15
      const int lane = tid & 63, ksg = tid >> 6;
      const int hi = lane >> 5, lo = lane & 31;
      const int j = jb * 32 + lo;
      float s = 0.f;
#pragma unroll
      for (int kq = 0; kq < 4; ++kq) {
        const int ks = ksg * 4 + kq;
        const float* src = cbk + (size_t)j * 256 + ks * 16 + 8 * hi;
        float f[8];
        *(float4*)(f + 0) = ((const float4*)src)[0];
        *(float4*)(f + 4) = ((const float4*)src)[1];
        union { f16x8 v; f16 e[8]; } h0, h1;
#pragma unroll
        for (int i = 0; i < 8; ++i) {
          s = fmaf(f[i], f[i], s);
          h2 t = split2(f[i]); h0.e[i] = t.hi; h1.e[i] = t.lo;
        }
        const size_t base = ((size_t)jb * 1024 + (size_t)ks * 64 + lane) * 8;
        *(f16x8*)(cbp0 + base) = h0.v;
        *(f16x8*)(cbp1 + base) = h1.v;
      }
      s += __shfl_xor(s, 32, 64);            // fold hi=0/1
      if (lane < 32) part[ksg][lane] = s;
      __syncthreads();
      if (tid < 32)
        hn[jb * 32 + tid] = 0.5f * (part[0][tid] + part[1][tid] + part[2][tid] + part[3][tid]);
    }
  } else {
    const int bid = bix - 272;               // 0..575
    const int b = bid / 18, rem = bid % 18;
    const int eq = rem / 9, ptile = rem % 9;
    const int p = ptile * 256 + tid;
    const bool valid = p < PT;
    const int pc = valid ? p : (PT - 1);
    float4 xv[8];
#pragma unroll
    for (int v = 0; v < 8; ++v)
      xv[v] = *(const float4*)(x + ((size_t)b * 8 + v) * SSN + 4 * pc);
    const int e0 = eq * 128;
    float4 wc[8], wn[8];
#pragma unroll
    for (int v = 0; v < 8; ++v) wc[v] = *(const float4*)(cw + (size_t)e0 * 32 + v * 4);
    for (int ep = e0; ep < e0 + 128; ++ep) {
      const int epn = (ep + 1 < e0 + 128) ? ep + 1 : ep;
#pragma unroll
      for (int v = 0; v < 8; ++v) wn[v] = *(const float4*)(cw + (size_t)epn * 32 + v * 4);
      float a = cb[ep];
#pragma unroll
      for (int v = 0; v < 8; ++v) {
        a = fmaf(xv[v].x, wc[v].x, a);
        a = fmaf(xv[v].y, wc[v].y, a);
        a = fmaf(xv[v].z, wc[v].z, a);
        a = fmaf(xv[v].w, wc[v].w, a);
      }
      a = fmaxf(a, 0.f);
      if (valid) {
        const h2 s = split2(a);
        const size_t o = ((size_t)b * EE + ep) * PT + p;
        y0[o] = s.hi; y1[o] = s.lo;
      }
#pragma unroll
      for (int v = 0; v < 8; ++v) wc[v] = wn[v];
    }
  }
}

// ================= k2p: linear GEMM, K-split-2, partial f32 via atomicAdd =====
// 512 blocks = 2 kh(K=2048) x 128 M-tiles(128w) x 2 N-halves(128eo); 512 thr = 8 waves.
// Wave-tile 32x64 (R7 economy). Single-buffer LDS (41KB) -> 2 blocks/CU, 4 waves/SIMD.
__global__ __launch_bounds__(512, 4)
void k2p(const f16* __restrict__ yh0, const f16* __restrict__ yh1,
         const f16* __restrict__ lwp0, const f16* __restrict__ lwp1,
         float* __restrict__ pacc)
{
  __shared__ __align__(16) f16 ysh[2][4][528];      // [limb][ke][pos] 8.4KB
  __shared__ __align__(16) f16 bsh[4][4][2][512];   // [ke][nb][limb][frag] 32KB
  const int tid = threadIdx.x;
  // XCD-aware swizzle over 512 blocks (bijective: 512 % 8 == 0)
  const int sw = (blockIdx.x & 7) * 64 + (blockIdx.x >> 3);
  const int kh = sw >> 8;                 // K-half
  const int rest = sw & 255;
  const int mt = rest >> 1, nh = rest & 1;
  const int b  = mt >> 2;
  const int p0 = (mt & 3) * 512;
  const int lane = tid & 63, wv = tid >> 6;
  const int mg = wv >> 1, nqw = wv & 1;   // compute roles: 4m x 2n
  const int hi = lane >> 5, lo = lane & 31;

  // B staging roles: wave wv stages ke=wv>>1, nb pair (wv&1)*2 .. +1 (both limbs)
  const int bke = wv >> 1, bnb0 = (wv & 1) * 2;
  const f16* bs00 = lwp0 + ((size_t)(nh * 4 + bnb0) * 256 + kh * 128 + bke) * 512 + lane * 8;
  const f16* bs01 = lwp1 + ((size_t)(nh * 4 + bnb0) * 256 + kh * 128 + bke) * 512 + lane * 8;
  // nb+1 frag is +256 frags = +131072 elems
  // y staging: wave wv stages row (limb=wv>>2, ke=wv&3), 528 f16
  const int ylimb = wv >> 2, yke = wv & 3;
  const f16* ysrcp = ylimb ? yh1 : yh0;
  const size_t ybase0 = ((size_t)b * EE + kh * 128 + yke) * PT + p0 + lane * 8;
  const bool yext = lane < 2;

  f32x16 accH[2], accL[2];
#pragma unroll
  for (int n = 0; n < 2; ++n)
#pragma unroll
    for (int r = 0; r < 16; ++r) { accH[n][r] = 0.f; accL[n][r] = 0.f; }

  float4 br[4], ya; float4 yb{};

#define K2LOAD(ss_) do {                                                       \
    const size_t bo = (size_t)(ss_) * 2048;                                    \
    br[0] = *(const float4*)(bs00 + bo);                                       \
    br[1] = *(const float4*)(bs01 + bo);                                       \
    br[2] = *(const float4*)(bs00 + 131072 + bo);                              \
    br[3] = *(const float4*)(bs01 + 131072 + bo);                              \
    const size_t yo = ybase0 + (size_t)(ss_) * (4 * PT);                       \
    ya = *(const float4*)(ysrcp + yo);                                         \
    if (yext) yb = *(const float4*)(ysrcp + yo + 512);                         \
  } while (0)

#define K2WRITE() do {                                                         \
    *(float4*)&bsh[bke][bnb0    ][0][lane * 8] = br[0];                        \
    *(float4*)&bsh[bke][bnb0    ][1][lane * 8] = br[1];                        \
    *(float4*)&bsh[bke][bnb0 + 1][0][lane * 8] = br[2];                        \
    *(float4*)&bsh[bke][bnb0 + 1][1][lane * 8] = br[3];                        \
    f16* yd = &ysh[ylimb][yke][lane * 8];                                      \
    *(float4*)yd = ya;                                                         \
    if (yext) *(float4*)(yd + 512) = yb;                                       \
  } while (0)

  // prologue: tile 0 into LDS
  K2LOAD(0);
  K2WRITE();
  __syncthreads();

  for (int ss = 0; ss < 32; ++ss) {
    K2LOAD((ss < 31) ? ss + 1 : 31);   // regs live across MFMA (R7-proven pressure)

    const int aoff = 4 * (mg * 32 + lo) + 8 * hi;
#pragma unroll
    for (int ke = 0; ke < 4; ++ke) {
      const f16x8 a0 = ldsfrag(&ysh[0][ke][aoff]);
      const f16x8 a1 = ldsfrag(&ysh[1][ke][aoff]);
#pragma unroll
      for (int n = 0; n < 2; ++n) {
        const f16x8 b0 = *(const f16x8*)&bsh[ke][nqw * 2 + n][0][lane * 8];
        const f16x8 b1 = *(const f16x8*)&bsh[ke][nqw * 2 + n][1][lane * 8];
        accH[n] = MFMA16(a0, b0, accH[n]);
        accL[n] = MFMA16(a0, b1, accL[n]);
        accL[n] = MFMA16(a1, b0, accL[n]);
      }
    }
    __syncthreads();   // all reads of current tile done
    K2WRITE();         // overwrite with next tile
    __syncthreads();   // writes visible
  }
#undef K2LOAD
#undef K2WRITE

  // epilogue: partial v = accH + accL/2048 -> atomicAdd into f32 accumulator
#pragma unroll
  for (int n = 0; n < 2; ++n) {
    const int eo = nh * 128 + (nqw * 2 + n) * 32 + lo;
#pragma unroll
    for (int r = 0; r < 16; ++r) {
      const int wloc = mg * 32 + (r & 3) + 8 * (r >> 2) + 4 * hi;
      const float v = accH[n][r] + accL[n][r] * INV2048;
      atomicAdd(&pacc[(size_t)(mt * 128 + wloc) * EE + eo], v);
    }
  }
}

// ================= k3: combine + distance MFMA + argmax + gather ==============
__global__ __launch_bounds__(512, 1)
void k3_dist(const float* __restrict__ pacc, const float* __restrict__ lin_b,
             const f16* __restrict__ cbp0, const f16* __restrict__ cbp1,
             const float* __restrict__ hn, const float* __restrict__ cbk,
             float* __restrict__ out)
{
  __shared__ __align__(16) f16 esh[2][64][136];   // [limb][w][k-half]
  __shared__ float scs[4][64];
  __shared__ int   scj[4][64];
  __shared__ int   bestj[64];
  const int tid = threadIdx.x;
  const int w0 = blockIdx.x * 64;
  const int lane = tid & 63, wv = tid >> 6;
  const int m = wv & 1, jg = wv >> 1;
  const int hi = lane >> 5, lo = lane & 31;

  const f16* pBp[4][2];
  float hnv[4];
#pragma unroll
  for (int q = 0; q < 4; ++q) {
    const int jb = jg * 4 + q;
    pBp[q][0] = cbp0 + ((size_t)jb * 1024 + lane) * 8;
    pBp[q][1] = cbp1 + ((size_t)jb * 1024 + lane) * 8;
    hnv[q] = hn[jb * 32 + lo];
  }
  f32x16 accH[4], accL[4];
#pragma unroll
  for (int q = 0; q < 4; ++q)
#pragma unroll
    for (int r = 0; r < 16; ++r) { accH[q][r] = 0.f; accL[q][r] = 0.f; }

  const int ar = m * 32 + lo;
  f16x8 BA[4][2], BB[4][2];
#pragma unroll
  for (int q = 0; q < 4; ++q) {
    BA[q][0] = *(const f16x8*)(pBp[q][0]);
    BA[q][1] = *(const f16x8*)(pBp[q][1]);
  }

  for (int kh = 0; kh < 2; ++kh) {
    if (kh) __syncthreads();
    { // stage e-half from f32 partial sums + bias; split to limbs in LDS
      const int r = tid >> 3, c8 = tid & 7;
      const float* ps = pacc + (size_t)(w0 + r) * EE + kh * 128 + c8 * 16;
      const float* bsp = lin_b + kh * 128 + c8 * 16;
      float f[16], bb[16];
#pragma unroll
      for (int i = 0; i < 4; ++i) {
        *(float4*)(f + 4 * i)  = ((const float4*)ps)[i];
        *(float4*)(bb + 4 * i) = ((const float4*)bsp)[i];
      }
      union { f16x8 v; f16 e[8]; } h0[2], h1[2];
#pragma unroll
      for (int i = 0; i < 16; ++i) {
        const h2 s = split2(f[i] + bb[i]);
        h0[i >> 3].e[i & 7] = s.hi;
        h1[i >> 3].e[i & 7] = s.lo;
      }
      *(f16x8*)&esh[0][r][c8 * 16]     = h0[0].v;
      *(f16x8*)&esh[0][r][c8 * 16 + 8] = h0[1].v;
      *(f16x8*)&esh[1][r][c8 * 16]     = h1[0].v;
      *(f16x8*)&esh[1][r][c8 * 16 + 8] = h1[1].v;
    }
    __syncthreads();
#pragma unroll
    for (int ksl = 0; ksl < 8; ++ksl) {
      const int ks = kh * 8 + ksl;
      const int ksn = (ks < 15) ? ks + 1 : 15;
      const f16x8 a0 = *(const f16x8*)(&esh[0][ar][0] + ksl * 16 + 8 * hi);
      const f16x8 a1 = *(const f16x8*)(&esh[1][ar][0] + ksl * 16 + 8 * hi);
      if ((ks & 1) == 0) {
#pragma unroll
        for (int q = 0; q < 4; ++q) {
          BB[q][0] = *(const f16x8*)(pBp[q][0] + (size_t)ksn * 512);
          BB[q][1] = *(const f16x8*)(pBp[q][1] + (size_t)ksn * 512);
        }
#pragma unroll
        for (int q = 0; q < 4; ++q) {
          accH[q] = MFMA16(a0, BA[q][0], accH[q]);
          accL[q] = MFMA16(a0, BA[q][1], accL[q]);
          accL[q] = MFMA16(a1, BA[q][0], accL[q]);
        }
      } else {
#pragma unroll
        for (int q = 0; q < 4; ++q) {
          BA[q][0] = *(const f16x8*)(pBp[q][0] + (size_t)ksn * 512);
          BA[q][1] = *(const f16x8*)(pBp[q][1] + (size_t)ksn * 512);
        }
#pragma unroll
        for (int q = 0; q < 4; ++q) {
          accH[q] = MFMA16(a0, BB[q][0], accH[q]);
          accL[q] = MFMA16(a0, BB[q][1], accL[q]);
          accL[q] = MFMA16(a1, BB[q][0], accL[q]);
        }
      }
    }
  }

  // per-w argmax over j (min-index tie-break)
#pragma unroll
  for (int r = 0; r < 16; ++r) {
    float bs = accH[0][r] + accL[0][r] * INV2048 - hnv[0];
    int   bj = (jg * 4 + 0) * 32 + lo;
#pragma unroll
    for (int q = 1; q < 4; ++q) {
      const float s = accH[q][r] + accL[q][r] * INV2048 - hnv[q];
      const int   j = (jg * 4 + q) * 32 + lo;
      if (s > bs) { bs = s; bj = j; }   // ascending j: strict > keeps lowest
    }
#pragma unroll
    for (int d = 1; d < 32; d <<= 1) {
      const float os = __shfl_xor(bs, d, 64);
      const int   oj = __shfl_xor(bj, d, 64);
      if (os > bs || (os == bs && oj < bj)) { bs = os; bj = oj; }
    }
    if (lo == 0) {
      const int wloc = m * 32 + (r & 3) + 8 * (r >> 2) + 4 * hi;
      scs[jg][wloc] = bs; scj[jg][wloc] = bj;
    }
  }
  __syncthreads();
  if (tid < 64) {
    float bs = scs[0][tid]; int bj = scj[0][tid];
#pragma unroll
    for (int g = 1; g < 4; ++g) {
      const float s = scs[g][tid]; const int j = scj[g][tid];
      if (s > bs || (s == bs && j < bj)) { bs = s; bj = j; }
    }
    bestj[tid] = bj;
  }
  __syncthreads();
  { // gather codebook rows to output
    const int rr = tid >> 6;
    const int c4 = (tid & 63) * 4;
#pragma unroll
    for (int pass = 0; pass < 8; ++pass) {
      const int r = pass * 8 + rr;
      const int jb = bestj[r];
      const float4 v = *(const float4*)(cbk + (size_t)jb * EE + c4);
      *(float4*)(out + (size_t)(w0 + r) * EE + c4) = v;
    }
  }
}

// ================= fallback: R1 fused VALU kernel (known-good) =================
#define V 8
#define LAGS 4
#define WIN 64
#define STEP 16
#define CONV_OUT 16
#define WPB 16
#define TPB 256
#define NWORD 19
#define YSTRIDE 80
#define XSPAN 304
#define FOFF_YS   0
#define FOFF_XS   10240
#define FOFF_ES   10240
#define FOFF_SC   0
#define FOFF_SI   4096
#define FOFF_PS   8192
#define FOFF_PI   8448
#define FOFF_IW   8704
#define SMEM_FLOATS 14336

__device__ __forceinline__ float f4get(const float4& v, int i) {
  return i == 0 ? v.x : (i == 1 ? v.y : (i == 2 ? v.z : v.w));
}

__device__ __forceinline__ float conv_one(const float* xs, int p, const float4* cw, float cb0) {
  float a = cb0;
#pragma unroll
  for (int v = 0; v < V; ++v) {
    const float4 xv = *(const float4*)(xs + v * XSPAN + 4 * p);
    a = fmaf(xv.x, cw[v].x, a);
    a = fmaf(xv.y, cw[v].y, a);
    a = fmaf(xv.z, cw[v].z, a);
    a = fmaf(xv.w, cw[v].w, a);
  }
  return fmaxf(a, 0.0f);
}

__global__ __launch_bounds__(TPB, 2)
void tok_fused(const float* __restrict__ x, const float* __restrict__ conv_w,
               const float* __restrict__ conv_b, const float* __restrict__ lin_w,
               const float* __restrict__ lin_b, const float* __restrict__ cbk,
               float* __restrict__ out)
{
  __shared__ float smem[SMEM_FLOATS];
  float* ys = smem + FOFF_YS;
  float* xs = smem + FOFF_XS;
  float* es = smem + FOFF_ES;
  float* sc = smem + FOFF_SC;
  int*   si = (int*)(smem + FOFF_SI);
  float* ps = smem + FOFF_PS;
  int*   pi = (int*)(smem + FOFF_PI);
  int*   iw = (int*)(smem + FOFF_IW);
  const int tid = threadIdx.x;
  const int b   = blockIdx.x >> 5;
  const int t0  = (blockIdx.x & 31) * WPB;
  const float* xb = x + (size_t)b * V * SSN + (size_t)t0 * STEP;
#pragma unroll
  for (int v = 0; v < V; ++v)
    for (int j = tid; j < XSPAN; j += TPB)
      xs[v * XSPAN + j] = xb[(size_t)v * SSN + j];
  double accd[WPB];
#pragma unroll
  for (int w = 0; w < WPB; ++w) accd[w] = 0.0;
  for (int half = 0; half < 2; ++half) {
    __syncthreads();
    {
      const int ep  = half * 128 + (tid >> 1);
      const int row = ep & 127;
      float4 cw[V];
      const float4* cwp = (const float4*)(conv_w + (size_t)ep * (V * LAGS));
#pragma unroll
      for (int v = 0; v < V; ++v) cw[v] = cwp[v];
      const float cb0 = conv_b[ep];
      const int c0 = (tid & 1) ? 10 : 0;
      const int c1 = (tid & 1) ? NWORD : 10;
      for (int c = c0; c < c1; ++c) {
        const int p = 4 * c;
        float r0 = conv_one(xs, p + 0, cw, cb0);
        float r1 = conv_one(xs, p + 1, cw, cb0);
        float r2 = conv_one(xs, p + 2, cw, cb0);
        float r3 = conv_one(xs, p + 3, cw, cb0);
        *(float4*)(ys + row * YSTRIDE + 4 * c) = make_float4(r0, r1, r2, r3);
      }
    }
    __syncthreads();
    const float* lwbase = lin_w + (size_t)tid * (EE * CONV_OUT) + half * (128 * CONV_OUT);
    float4 nA, nB, nC, nD;
    {
      const float4* p4 = (const float4*)(lwbase);
      nA = p4[0]; nB = p4[1]; nC = p4[2]; nD = p4[3];
    }
    for (int er = 0; er < 128; ++er) {
      const float4 lA = nA, lB = nB, lC = nC, lD = nD;
      const int ern = (er + 1) & 127;
      {
        const float4* p4 = (const float4*)(lwbase + ern * CONV_OUT);
        nA = p4[0]; nB = p4[1]; nC = p4[2]; nD = p4[3];
      }
      float4 yr[NWORD];
      const float4* yp = (const float4*)(ys + er * YSTRIDE);
#pragma unroll
      for (int q = 0; q < NWORD; ++q) yr[q] = yp[q];
      float it[WPB];
#pragma unroll
      for (int w = 0; w < WPB; ++w) it[w] = 0.0f;
#pragma unroll
      for (int o = 0; o < CONV_OUT; ++o) {
        const float lw_o = f4get(o < 4 ? lA : (o < 8 ? lB : (o < 12 ? lC : lD)), o & 3);
#pragma unroll
        for (int w = 0; w < WPB; ++w) {
          const int p = 4 * w + o;
          it[w] = fmaf(lw_o, f4get(yr[p >> 2], p & 3), it[w]);
        }
      }
#pragma unroll
      for (int w = 0; w < WPB; ++w) accd[w] += (double)it[w];
    }
  }
#pragma unroll
  for (int w = 0; w < WPB; ++w)
    es[w * EE + tid] = (float)accd[w] + lin_b[tid];
  __syncthreads();
  float s_best[WPB];
  int   i_best[WPB];
#pragma unroll
  for (int jj = 0; jj < 2; ++jj) {
    const int j = tid + jj * 256;
    const float4* cbp = (const float4*)(cbk + (size_t)j * EE);
    double sdd[WPB];
    float  sd32[WPB];
#pragma unroll
    for (int w = 0; w < WPB; ++w) { sdd[w] = 0.0; sd32[w] = 0.f; }
    double ndd = 0.0;
    float  nd32 = 0.f;
    float4 c4n = cbp[0];
    for (int i16 = 0; i16 < 4; ++i16) {
      for (int i4i = 0; i4i < 16; ++i4i) {
        const int i4 = i16 * 16 + i4i;
        const float4 c4 = c4n;
        c4n = cbp[(i4 + 1 <= 63) ? (i4 + 1) : 63];
        nd32 = fmaf(c4.x, c4.x, nd32);
        nd32 = fmaf(c4.y, c4.y, nd32);
        nd32 = fmaf(c4.z, c4.z, nd32);
        nd32 = fmaf(c4.w, c4.w, nd32);
#pragma unroll
        for (int w = 0; w < WPB; ++w) {
          const float4 e4 = *(const float4*)(es + w * EE + i4 * 4);
          sd32[w] = fmaf(c4.x, e4.x, sd32[w]);
          sd32[w] = fmaf(c4.y, e4.y, sd32[w]);
          sd32[w] = fmaf(c4.z, e4.z, sd32[w]);
          sd32[w] = fmaf(c4.w, e4.w, sd32[w]);
        }
      }
#pragma unroll
      for (int w = 0; w < WPB; ++w) { sdd[w] += (double)sd32[w]; sd32[w] = 0.f; }
      ndd += (double)nd32; nd32 = 0.f;
    }
#pragma unroll
    for (int w = 0; w < WPB; ++w) {
      const float s = (float)(sdd[w] - 0.5 * ndd);
      if (jj == 0) { s_best[w] = s; i_best[w] = j; }
      else if (s > s_best[w]) { s_best[w] = s; i_best[w] = j; }
    }
  }
#pragma unroll
  for (int w = 0; w < WPB; ++w) {
    sc[w * EE + tid] = s_best[w];
    si[w * EE + tid] = i_best[w];
  }
  __syncthreads();
  {
    const int w = tid >> 4, seg = tid & 15;
    float mm = -INFINITY; int mi = 0x7fffffff;
    for (int t = seg * 16; t < seg * 16 + 16; ++t) {
      const float s = sc[w * EE + t];
      const int   jx = si[w * EE + t];
      if (s > mm || (s == mm && jx < mi)) { mm = s; mi = jx; }
    }
    ps[w * 16 + seg] = mm; pi[w * 16 + seg] = mi;
  }
  __syncthreads();
  if (tid < WPB) {
    const int w = tid;
    float mm = -INFINITY; int mi = 0x7fffffff;
    for (int t = 0; t < 16; ++t) {
      const float s = ps[w * 16 + t];
      const int   jx = pi[w * 16 + t];
      if (s > mm || (s == mm && jx < mi)) { mm = s; mi = jx; }
    }
    iw[w] = mi;
  }
  __syncthreads();
  const size_t outb = ((size_t)b * TTOT + t0) * EE;
#pragma unroll
  for (int w = 0; w < WPB; ++w)
    out[outb + (size_t)w * EE + tid] = cbk[(size_t)iw[w] * EE + tid];
}

// ================= launch =================
extern "C" void kernel_launch(void* const* d_in, const int* in_sizes, int n_in,
                              void* d_out, int out_size, void* d_ws, size_t ws_size,
                              hipStream_t stream) {
  const float* x      = (const float*)d_in[0];
  const float* conv_w = (const float*)d_in[1];
  const float* conv_b = (const float*)d_in[2];
  const float* lin_w  = (const float*)d_in[3];
  const float* lin_b  = (const float*)d_in[4];
  const float* cbk    = (const float*)d_in[5];
  float* out = (float*)d_out;

  if (ws_size < WS_NEED) {
    tok_fused<<<dim3(32 * 32), dim3(TPB), 0, stream>>>(x, conv_w, conv_b, lin_w, lin_b, cbk, out);
    return;
  }
  char* ws = (char*)d_ws;
  f16*   y0   = (f16*)(ws + OFF_Y0);
  f16*   y1   = (f16*)(ws + OFF_Y1);
  f16*   lwp0 = (f16*)(ws + OFF_LW0);
  f16*   lwp1 = (f16*)(ws + OFF_LW1);
  f16*   cbp0 = (f16*)(ws + OFF_CB0);
  f16*   cbp1 = (f16*)(ws + OFF_CB1);
  float* hn   = (float*)(ws + OFF_HN);
  float* pacc = (float*)(ws + OFF_E0);

  hipMemsetAsync(pacc, 0, PACC_BYTES, stream);
  k01<<<848, 256, 0, stream>>>(lin_w, cbk, lwp0, lwp1, cbp0, cbp1, hn,
                               x, conv_w, conv_b, y0, y1);
  k2p<<<512, 512, 0, stream>>>(y0, y1, lwp0, lwp1, pacc);
  k3_dist<<<256, 512, 0, stream>>>(pacc, lin_b, cbp0, cbp1, hn, cbk, out);
}

// Round 12
// 252.573 us; speedup vs baseline: 1.0784x; 1.0784x over previous
//
#include <hip/hip_runtime.h>

typedef _Float16 f16;
typedef _Float16 f16x4 __attribute__((ext_vector_type(4)));
typedef _Float16 f16x8 __attribute__((ext_vector_type(8)));
typedef float    f32x16 __attribute__((ext_vector_type(16)));

#define NB 32
#define TTOT 512
#define SSN 8256
#define PT 2064
#define EE 256
#define KCB 512

// ---------------- ws layout (bytes) ----------------
#define YB   ((size_t)NB*EE*PT*2)
#define LWB  ((size_t)EE*4096*2)
#define CBB  ((size_t)KCB*EE*2)
#define EBB  ((size_t)16384*EE*2)
#define OFF_Y0  ((size_t)0)
#define OFF_Y1  (YB)
#define OFF_LW0 (2*YB)
#define OFF_LW1 (2*YB + LWB)
#define OFF_CB0 (2*YB + 2*LWB)
#define OFF_CB1 (2*YB + 2*LWB + CBB)
#define OFF_HN  (2*YB + 2*LWB + 2*CBB)
#define OFF_E0  (OFF_HN + 4096)            // middle path: eh0 | split path: pacc0
#define OFF_E1  (OFF_E0 + EBB)
#define WS_NEED (OFF_E1 + EBB)             // 89.1 MB (middle path)
#define PACC_BYTES ((size_t)16384*EE*4)    // 16.78 MB
#define OFF_P1  (WS_NEED)                  // split path: pacc1
#define WS_NEED2 (WS_NEED + PACC_BYTES)    // 105.9 MB

#define INV2048 4.8828125e-4f

struct h2 { f16 hi, lo; };
__device__ __forceinline__ h2 split2(float v) {
  h2 r;
  r.hi = (f16)v;
  r.lo = (f16)((v - (float)r.hi) * 2048.0f);
  return r;
}

__device__ __forceinline__ f16x8 ldsfrag(const f16* p) {
  union { f16x8 v8; f16x4 v4[2]; } u;
  u.v4[0] = *(const f16x4*)p;
  u.v4[1] = *(const f16x4*)(p + 4);
  return u.v8;
}

#define MFMA16(a,b,c) __builtin_amdgcn_mfma_f32_32x32x16_f16(a, b, c, 0, 0, 0)

// ================= k01: fused repack (k0) + conv (k1) =================
__global__ __launch_bounds__(256, 2)
void k01(const float* __restrict__ lin_w, const float* __restrict__ cbk,
         f16* __restrict__ lwp0, f16* __restrict__ lwp1,
         f16* __restrict__ cbp0, f16* __restrict__ cbp1, float* __restrict__ hn,
         const float* __restrict__ x, const float* __restrict__ cw,
         const float* __restrict__ cb, f16* __restrict__ y0, f16* __restrict__ y1)
{
  __shared__ float part[4][32];
  const int tid = threadIdx.x;
  const int bix = blockIdx.x;
  if (bix < 272) {
    const int bid = bix;
    if (bid < 256) {
      const int eo = bid, nb = eo >> 5, lo = eo & 31;
      const int ep = tid;
      const float* src = lin_w + (size_t)eo * 4096 + ep * 16;
      float f[16];
      *(float4*)(f + 0)  = ((const float4*)src)[0];
      *(float4*)(f + 4)  = ((const float4*)src)[1];
      *(float4*)(f + 8)  = ((const float4*)src)[2];
      *(float4*)(f + 12) = ((const float4*)src)[3];
      union { f16x8 v; f16 e[8]; } a0, a1, b0, b1;
#pragma unroll
      for (int i = 0; i < 8; ++i) {
        { h2 s = split2(f[i]);     a0.e[i] = s.hi; a1.e[i] = s.lo; }
        { h2 s = split2(f[i + 8]); b0.e[i] = s.hi; b1.e[i] = s.lo; }
      }
      const size_t base = ((size_t)nb * 16384 + (size_t)ep * 64 + lo) * 8;
      *(f16x8*)(lwp0 + base)       = a0.v;   // lane hi=0 slot
      *(f16x8*)(lwp0 + base + 256) = b0.v;   // lane hi=1 slot
      *(f16x8*)(lwp1 + base)       = a1.v;
      *(f16x8*)(lwp1 + base + 256) = b1.v;
    } else {
      const int jb = bid - 256;              // 0..15
      const int lane = tid & 63, ksg = tid >> 6;
      const int hi = lane >> 5, lo = lane & 31;
      const int j = jb * 32 + lo;
      float s = 0.f;
#pragma unroll
      for (int kq = 0; kq < 4; ++kq) {
        const int ks = ksg * 4 + kq;
        const float* src = cbk + (size_t)j * 256 + ks * 16 + 8 * hi;
        float f[8];
        *(float4*)(f + 0) = ((const float4*)src)[0];
        *(float4*)(f + 4) = ((const float4*)src)[1];
        union { f16x8 v; f16 e[8]; } h0, h1;
#pragma unroll
        for (int i = 0; i < 8; ++i) {
          s = fmaf(f[i], f[i], s);
          h2 t = split2(f[i]); h0.e[i] = t.hi; h1.e[i] = t.lo;
        }
        const size_t base = ((size_t)jb * 1024 + (size_t)ks * 64 + lane) * 8;
        *(f16x8*)(cbp0 + base) = h0.v;
        *(f16x8*)(cbp1 + base) = h1.v;
      }
      s += __shfl_xor(s, 32, 64);            // fold hi=0/1
      if (lane < 32) part[ksg][lane] = s;
      __syncthreads();
      if (tid < 32)
        hn[jb * 32 + tid] = 0.5f * (part[0][tid] + part[1][tid] + part[2][tid] + part[3][tid]);
    }
  } else {
    const int bid = bix - 272;               // 0..575
    const int b = bid / 18, rem = bid % 18;
    const int eq = rem / 9, ptile = rem % 9;
    const int p = ptile * 256 + tid;
    const bool valid = p < PT;
    const int pc = valid ? p : (PT - 1);
    float4 xv[8];
#pragma unroll
    for (int v = 0; v < 8; ++v)
      xv[v] = *(const float4*)(x + ((size_t)b * 8 + v) * SSN + 4 * pc);
    const int e0 = eq * 128;
    float4 wc[8], wn[8];
#pragma unroll
    for (int v = 0; v < 8; ++v) wc[v] = *(const float4*)(cw + (size_t)e0 * 32 + v * 4);
    for (int ep = e0; ep < e0 + 128; ++ep) {
      const int epn = (ep + 1 < e0 + 128) ? ep + 1 : ep;
#pragma unroll
      for (int v = 0; v < 8; ++v) wn[v] = *(const float4*)(cw + (size_t)epn * 32 + v * 4);
      float a = cb[ep];
#pragma unroll
      for (int v = 0; v < 8; ++v) {
        a = fmaf(xv[v].x, wc[v].x, a);
        a = fmaf(xv[v].y, wc[v].y, a);
        a = fmaf(xv[v].z, wc[v].z, a);
        a = fmaf(xv[v].w, wc[v].w, a);
      }
      a = fmaxf(a, 0.f);
      if (valid) {
        const h2 s = split2(a);
        const size_t o = ((size_t)b * EE + ep) * PT + p;
        y0[o] = s.hi; y1[o] = s.lo;
      }
#pragma unroll
      for (int v = 0; v < 8; ++v) wc[v] = wn[v];
    }
  }
}

// ================= k2p: linear GEMM, K-split-2, plain-store partials ==========
// 512 blocks = 2 kh(K=2048) x 128 M-tiles(128w) x 2 N-halves(128eo); 512 thr = 8 waves.
// Wave-tile 32x64. Single-buffer LDS (41KB) -> 2 blocks/CU, 4 waves/SIMD.
__global__ __launch_bounds__(512, 4)
void k2p(const f16* __restrict__ yh0, const f16* __restrict__ yh1,
         const f16* __restrict__ lwp0, const f16* __restrict__ lwp1,
         float* __restrict__ pacc0, float* __restrict__ pacc1)
{
  __shared__ __align__(16) f16 ysh[2][4][528];      // [limb][ke][pos] 8.4KB
  __shared__ __align__(16) f16 bsh[4][4][2][512];   // [ke][nb][limb][frag] 32KB
  const int tid = threadIdx.x;
  // XCD-aware swizzle over 512 blocks (bijective: 512 % 8 == 0)
  const int sw = (blockIdx.x & 7) * 64 + (blockIdx.x >> 3);
  const int kh = sw >> 8;                 // K-half
  const int rest = sw & 255;
  const int mt = rest >> 1, nh = rest & 1;
  const int b  = mt >> 2;
  const int p0 = (mt & 3) * 512;
  const int lane = tid & 63, wv = tid >> 6;
  const int mg = wv >> 1, nqw = wv & 1;   // compute roles: 4m x 2n
  const int hi = lane >> 5, lo = lane & 31;

  // B staging roles: wave wv stages ke=wv>>1, nb pair (wv&1)*2 .. +1 (both limbs)
  const int bke = wv >> 1, bnb0 = (wv & 1) * 2;
  const f16* bs00 = lwp0 + ((size_t)(nh * 4 + bnb0) * 256 + kh * 128 + bke) * 512 + lane * 8;
  const f16* bs01 = lwp1 + ((size_t)(nh * 4 + bnb0) * 256 + kh * 128 + bke) * 512 + lane * 8;
  // nb+1 frag is +256 frags = +131072 elems
  // y staging: wave wv stages row (limb=wv>>2, ke=wv&3), 528 f16
  const int ylimb = wv >> 2, yke = wv & 3;
  const f16* ysrcp = ylimb ? yh1 : yh0;
  const size_t ybase0 = ((size_t)b * EE + kh * 128 + yke) * PT + p0 + lane * 8;
  const bool yext = lane < 2;

  f32x16 accH[2], accL[2];
#pragma unroll
  for (int n = 0; n < 2; ++n)
#pragma unroll
    for (int r = 0; r < 16; ++r) { accH[n][r] = 0.f; accL[n][r] = 0.f; }

  float4 br[4], ya; float4 yb{};

#define K2LOAD(ss_) do {                                                       \
    const size_t bo = (size_t)(ss_) * 2048;                                    \
    br[0] = *(const float4*)(bs00 + bo);                                       \
    br[1] = *(const float4*)(bs01 + bo);                                       \
    br[2] = *(const float4*)(bs00 + 131072 + bo);                              \
    br[3] = *(const float4*)(bs01 + 131072 + bo);                              \
    const size_t yo = ybase0 + (size_t)(ss_) * (4 * PT);                       \
    ya = *(const float4*)(ysrcp + yo);                                         \
    if (yext) yb = *(const float4*)(ysrcp + yo + 512);                         \
  } while (0)

#define K2WRITE() do {                                                         \
    *(float4*)&bsh[bke][bnb0    ][0][lane * 8] = br[0];                        \
    *(float4*)&bsh[bke][bnb0    ][1][lane * 8] = br[1];                        \
    *(float4*)&bsh[bke][bnb0 + 1][0][lane * 8] = br[2];                        \
    *(float4*)&bsh[bke][bnb0 + 1][1][lane * 8] = br[3];                        \
    f16* yd = &ysh[ylimb][yke][lane * 8];                                      \
    *(float4*)yd = ya;                                                         \
    if (yext) *(float4*)(yd + 512) = yb;                                       \
  } while (0)

  // prologue: tile 0 into LDS
  K2LOAD(0);
  K2WRITE();
  __syncthreads();

  for (int ss = 0; ss < 32; ++ss) {
    K2LOAD((ss < 31) ? ss + 1 : 31);   // regs live across MFMA

    const int aoff = 4 * (mg * 32 + lo) + 8 * hi;
#pragma unroll
    for (int ke = 0; ke < 4; ++ke) {
      const f16x8 a0 = ldsfrag(&ysh[0][ke][aoff]);
      const f16x8 a1 = ldsfrag(&ysh[1][ke][aoff]);
#pragma unroll
      for (int n = 0; n < 2; ++n) {
        const f16x8 b0 = *(const f16x8*)&bsh[ke][nqw * 2 + n][0][lane * 8];
        const f16x8 b1 = *(const f16x8*)&bsh[ke][nqw * 2 + n][1][lane * 8];
        accH[n] = MFMA16(a0, b0, accH[n]);
        accL[n] = MFMA16(a0, b1, accL[n]);
        accL[n] = MFMA16(a1, b0, accL[n]);
      }
    }
    __syncthreads();   // all reads of current tile done
    K2WRITE();         // overwrite with next tile
    __syncthreads();   // writes visible
  }
#undef K2LOAD
#undef K2WRITE

  // epilogue: partial v = accH + accL/2048 -> plain store (own kh buffer)
  float* pacc = kh ? pacc1 : pacc0;
#pragma unroll
  for (int n = 0; n < 2; ++n) {
    const int eo = nh * 128 + (nqw * 2 + n) * 32 + lo;
#pragma unroll
    for (int r = 0; r < 16; ++r) {
      const int wloc = mg * 32 + (r & 3) + 8 * (r >> 2) + 4 * hi;
      pacc[(size_t)(mt * 128 + wloc) * EE + eo] = accH[n][r] + accL[n][r] * INV2048;
    }
  }
}

// ============ k3s: combine(pacc0+pacc1+bias) + distance MFMA + argmax =========
__global__ __launch_bounds__(512, 1)
void k3s(const float* __restrict__ pacc0, const float* __restrict__ pacc1,
         const float* __restrict__ lin_b,
         const f16* __restrict__ cbp0, const f16* __restrict__ cbp1,
         const float* __restrict__ hn, const float* __restrict__ cbk,
         float* __restrict__ out)
{
  __shared__ __align__(16) f16 esh[2][64][136];   // [limb][w][k-half]
  __shared__ float scs[4][64];
  __shared__ int   scj[4][64];
  __shared__ int   bestj[64];
  const int tid = threadIdx.x;
  const int w0 = blockIdx.x * 64;
  const int lane = tid & 63, wv = tid >> 6;
  const int m = wv & 1, jg = wv >> 1;
  const int hi = lane >> 5, lo = lane & 31;

  const f16* pBp[4][2];
  float hnv[4];
#pragma unroll
  for (int q = 0; q < 4; ++q) {
    const int jb = jg * 4 + q;
    pBp[q][0] = cbp0 + ((size_t)jb * 1024 + lane) * 8;
    pBp[q][1] = cbp1 + ((size_t)jb * 1024 + lane) * 8;
    hnv[q] = hn[jb * 32 + lo];
  }
  f32x16 accH[4], accL[4];
#pragma unroll
  for (int q = 0; q < 4; ++q)
#pragma unroll
    for (int r = 0; r < 16; ++r) { accH[q][r] = 0.f; accL[q][r] = 0.f; }

  const int ar = m * 32 + lo;
  f16x8 BA[4][2], BB[4][2];
#pragma unroll
  for (int q = 0; q < 4; ++q) {
    BA[q][0] = *(const f16x8*)(pBp[q][0]);
    BA[q][1] = *(const f16x8*)(pBp[q][1]);
  }

  for (int kh = 0; kh < 2; ++kh) {
    if (kh) __syncthreads();
    { // stage e-half = pacc0 + pacc1 + bias; split to limbs in LDS
      const int r = tid >> 3, c8 = tid & 7;
      const size_t idx = (size_t)(w0 + r) * EE + kh * 128 + c8 * 16;
      const float* ps0 = pacc0 + idx;
      const float* ps1 = pacc1 + idx;
      const float* bsp = lin_b + kh * 128 + c8 * 16;
      float f[16];
#pragma unroll
      for (int i = 0; i < 4; ++i) {
        const float4 v0 = ((const float4*)ps0)[i];
        const float4 v1 = ((const float4*)ps1)[i];
        const float4 bb = ((const float4*)bsp)[i];
        f[4 * i + 0] = v0.x + v1.x + bb.x;
        f[4 * i + 1] = v0.y + v1.y + bb.y;
        f[4 * i + 2] = v0.z + v1.z + bb.z;
        f[4 * i + 3] = v0.w + v1.w + bb.w;
      }
      union { f16x8 v; f16 e[8]; } h0[2], h1[2];
#pragma unroll
      for (int i = 0; i < 16; ++i) {
        const h2 s = split2(f[i]);
        h0[i >> 3].e[i & 7] = s.hi;
        h1[i >> 3].e[i & 7] = s.lo;
      }
      *(f16x8*)&esh[0][r][c8 * 16]     = h0[0].v;
      *(f16x8*)&esh[0][r][c8 * 16 + 8] = h0[1].v;
      *(f16x8*)&esh[1][r][c8 * 16]     = h1[0].v;
      *(f16x8*)&esh[1][r][c8 * 16 + 8] = h1[1].v;
    }
    __syncthreads();
#pragma unroll
    for (int ksl = 0; ksl < 8; ++ksl) {
      const int ks = kh * 8 + ksl;
      const int ksn = (ks < 15) ? ks + 1 : 15;
      const f16x8 a0 = *(const f16x8*)(&esh[0][ar][0] + ksl * 16 + 8 * hi);
      const f16x8 a1 = *(const f16x8*)(&esh[1][ar][0] + ksl * 16 + 8 * hi);
      if ((ks & 1) == 0) {
#pragma unroll
        for (int q = 0; q < 4; ++q) {
          BB[q][0] = *(const f16x8*)(pBp[q][0] + (size_t)ksn * 512);
          BB[q][1] = *(const f16x8*)(pBp[q][1] + (size_t)ksn * 512);
        }
#pragma unroll
        for (int q = 0; q < 4; ++q) {
          accH[q] = MFMA16(a0, BA[q][0], accH[q]);
          accL[q] = MFMA16(a0, BA[q][1], accL[q]);
          accL[q] = MFMA16(a1, BA[q][0], accL[q]);
        }
      } else {
#pragma unroll
        for (int q = 0; q < 4; ++q) {
          BA[q][0] = *(const f16x8*)(pBp[q][0] + (size_t)ksn * 512);
          BA[q][1] = *(const f16x8*)(pBp[q][1] + (size_t)ksn * 512);
        }
#pragma unroll
        for (int q = 0; q < 4; ++q) {
          accH[q] = MFMA16(a0, BB[q][0], accH[q]);
          accL[q] = MFMA16(a0, BB[q][1], accL[q]);
          accL[q] = MFMA16(a1, BB[q][0], accL[q]);
        }
      }
    }
  }

  // per-w argmax over j (min-index tie-break)
#pragma unroll
  for (int r = 0; r < 16; ++r) {
    float bs = accH[0][r] + accL[0][r] * INV2048 - hnv[0];
    int   bj = (jg * 4 + 0) * 32 + lo;
#pragma unroll
    for (int q = 1; q < 4; ++q) {
      const float s = accH[q][r] + accL[q][r] * INV2048 - hnv[q];
      const int   j = (jg * 4 + q) * 32 + lo;
      if (s > bs) { bs = s; bj = j; }   // ascending j: strict > keeps lowest
    }
#pragma unroll
    for (int d = 1; d < 32; d <<= 1) {
      const float os = __shfl_xor(bs, d, 64);
      const int   oj = __shfl_xor(bj, d, 64);
      if (os > bs || (os == bs && oj < bj)) { bs = os; bj = oj; }
    }
    if (lo == 0) {
      const int wloc = m * 32 + (r & 3) + 8 * (r >> 2) + 4 * hi;
      scs[jg][wloc] = bs; scj[jg][wloc] = bj;
    }
  }
  __syncthreads();
  if (tid < 64) {
    float bs = scs[0][tid]; int bj = scj[0][tid];
#pragma unroll
    for (int g = 1; g < 4; ++g) {
      const float s = scs[g][tid]; const int j = scj[g][tid];
      if (s > bs || (s == bs && j < bj)) { bs = s; bj = j; }
    }
    bestj[tid] = bj;
  }
  __syncthreads();
  { // gather codebook rows to output
    const int rr = tid >> 6;
    const int c4 = (tid & 63) * 4;
#pragma unroll
    for (int pass = 0; pass < 8; ++pass) {
      const int r = pass * 8 + rr;
      const int jb = bestj[r];
      const float4 v = *(const float4*)(cbk + (size_t)jb * EE + c4);
      *(float4*)(out + (size_t)(w0 + r) * EE + c4) = v;
    }
  }
}

// ======== middle path (ws < WS_NEED2): R7-proven k2 (eh limbs) + k3_old =======
__global__ __launch_bounds__(512, 1)
void k2_linear(const f16* __restrict__ yh0, const f16* __restrict__ yh1,
               const f16* __restrict__ lwp0, const f16* __restrict__ lwp1,
               const float* __restrict__ lin_b,
               f16* __restrict__ eh0, f16* __restrict__ eh1)
{
  __shared__ __align__(16) f16 ysh[2][2][4][528];       // [buf][limb][ke][pos]
  __shared__ __align__(16) f16 bsh[2][4][4][2][512];    // [buf][ke][nb][limb][frag]
  const int tid = threadIdx.x;
  const int sw = (blockIdx.x & 7) * 32 + (blockIdx.x >> 3);
  const int nh = sw >> 7, mt = sw & 127;
  const int b = mt >> 2;
  const int p0 = (mt & 3) * 512;
  const int lane = tid & 63, wv = tid >> 6;
  const int m = wv >> 1, nq = wv & 1;
  const int hi = lane >> 5, lo = lane & 31;
  const int aoff = 4 * (m * 32 + lo) + 8 * hi;

  const int bke = wv >> 1;
  const int bnb0 = (wv & 1) * 2;
  const f16* bs[2][2];
#pragma unroll
  for (int j = 0; j < 2; ++j) {
    bs[j][0] = lwp0 + ((size_t)(nh * 4 + bnb0 + j) * 256) * 512 + lane * 8;
    bs[j][1] = lwp1 + ((size_t)(nh * 4 + bnb0 + j) * 256) * 512 + lane * 8;
  }
  const int ylimb = wv >> 2, yke = wv & 3;
  const f16* ysrcp = ylimb ? yh1 : yh0;
  const size_t ybase0 = ((size_t)b * EE + yke) * PT + p0 + lane * 8;

  f32x16 accH[2], accL[2];
#pragma unroll
  for (int n = 0; n < 2; ++n)
#pragma unroll
    for (int r = 0; r < 16; ++r) { accH[n][r] = 0.f; accL[n][r] = 0.f; }

  { // prologue: stage ss=0 into buf0
    const size_t epo = (size_t)bke * 512;
    float4 br[4];
#pragma unroll
    for (int i = 0; i < 4; ++i) br[i] = *(const float4*)(bs[i >> 1][i & 1] + epo);
    const float4 ya = *(const float4*)(ysrcp + ybase0);
    float4 yb{};
    if (lane < 2) yb = *(const float4*)(ysrcp + ybase0 + 512);
#pragma unroll
    for (int i = 0; i < 4; ++i)
      *(float4*)&bsh[0][bke][bnb0 + (i >> 1)][i & 1][lane * 8] = br[i];
    f16* yd = &ysh[0][ylimb][yke][lane * 8];
    *(float4*)yd = ya;
    if (lane < 2) *(float4*)(yd + 512) = yb;
  }
  __syncthreads();

  for (int ss = 0; ss < 64; ++ss) {
    const int cur = ss & 1;
    const int ssn = (ss < 63) ? ss + 1 : 63;
    const size_t epo = (size_t)(ssn * 4 + bke) * 512;
    float4 br[4];
#pragma unroll
    for (int i = 0; i < 4; ++i) br[i] = *(const float4*)(bs[i >> 1][i & 1] + epo);
    const size_t yb0 = ybase0 + (size_t)ssn * 4 * PT;
    const float4 ya = *(const float4*)(ysrcp + yb0);
    float4 yb{};
    if (lane < 2) yb = *(const float4*)(ysrcp + yb0 + 512);

#pragma unroll
    for (int ke = 0; ke < 4; ++ke) {
      const f16x8 a0 = ldsfrag(&ysh[cur][0][ke][aoff]);
      const f16x8 a1 = ldsfrag(&ysh[cur][1][ke][aoff]);
#pragma unroll
      for (int n = 0; n < 2; ++n) {
        const f16x8 b0 = *(const f16x8*)&bsh[cur][ke][nq * 2 + n][0][lane * 8];
        const f16x8 b1 = *(const f16x8*)&bsh[cur][ke][nq * 2 + n][1][lane * 8];
        accH[n] = MFMA16(a0, b0, accH[n]);
        accL[n] = MFMA16(a0, b1, accL[n]);
        accL[n] = MFMA16(a1, b0, accL[n]);
      }
    }
    {
      const int nxt = cur ^ 1;
#pragma unroll
      for (int i = 0; i < 4; ++i)
        *(float4*)&bsh[nxt][bke][bnb0 + (i >> 1)][i & 1][lane * 8] = br[i];
      f16* yd = &ysh[nxt][ylimb][yke][lane * 8];
      *(float4*)yd = ya;
      if (lane < 2) *(float4*)(yd + 512) = yb;
    }
    __syncthreads();
  }

#pragma unroll
  for (int n = 0; n < 2; ++n) {
    const int eo = nh * 128 + (nq * 2 + n) * 32 + lo;
    const float lb = lin_b[eo];
#pragma unroll
    for (int r = 0; r < 16; ++r) {
      const int wloc = m * 32 + (r & 3) + 8 * (r >> 2) + 4 * hi;
      const float v = accH[n][r] + accL[n][r] * INV2048 + lb;
      const h2 s = split2(v);
      const size_t o = (size_t)(mt * 128 + wloc) * EE + eo;
      eh0[o] = s.hi; eh1[o] = s.lo;
    }
  }
}

__global__ __launch_bounds__(512, 1)
void k3_old(const f16* __restrict__ eh0, const f16* __restrict__ eh1,
            const f16* __restrict__ cbp0, const f16* __restrict__ cbp1,
            const float* __restrict__ hn, const float* __restrict__ cbk,
            float* __restrict__ out)
{
  __shared__ __align__(16) f16 esh[2][64][136];
  __shared__ float scs[4][64];
  __shared__ int   scj[4][64];
  __shared__ int   bestj[64];
  const int tid = threadIdx.x;
  const int w0 = blockIdx.x * 64;
  const int lane = tid & 63, wv = tid >> 6;
  const int m = wv & 1, jg = wv >> 1;
  const int hi = lane >> 5, lo = lane & 31;

  const f16* pBp[4][2];
  float hnv[4];
#pragma unroll
  for (int q = 0; q < 4; ++q) {
    const int jb = jg * 4 + q;
    pBp[q][0] = cbp0 + ((size_t)jb * 1024 + lane) * 8;
    pBp[q][1] = cbp1 + ((size_t)jb * 1024 + lane) * 8;
    hnv[q] = hn[jb * 32 + lo];
  }
  f32x16 accH[4], accL[4];
#pragma unroll
  for (int q = 0; q < 4; ++q)
#pragma unroll
    for (int r = 0; r < 16; ++r) { accH[q][r] = 0.f; accL[q][r] = 0.f; }

  const int ar = m * 32 + lo;
  f16x8 BA[4][2], BB[4][2];
#pragma unroll
  for (int q = 0; q < 4; ++q) {
    BA[q][0] = *(const f16x8*)(pBp[q][0]);
    BA[q][1] = *(const f16x8*)(pBp[q][1]);
  }

  for (int kh = 0; kh < 2; ++kh) {
    if (kh) __syncthreads();
    {
      const int r = tid >> 3, c8 = tid & 7;
      const f16* s0 = eh0 + (size_t)(w0 + r) * EE + kh * 128;
      const f16* s1 = eh1 + (size_t)(w0 + r) * EE + kh * 128;
#pragma unroll
      for (int i = 0; i < 2; ++i) {
        const int c = (c8 * 2 + i) * 8;
        *(float4*)&esh[0][r][c] = *(const float4*)(s0 + c);
        *(float4*)&esh[1][r][c] = *(const float4*)(s1 + c);
      }
    }
    __syncthreads();
#pragma unroll
    for (int ksl = 0; ksl < 8; ++ksl) {
      const int ks = kh * 8 + ksl;
      const int ksn = (ks < 15) ? ks + 1 : 15;
      const f16x8 a0 = *(const f16x8*)(&esh[0][ar][0] + ksl * 16 + 8 * hi);
      const f16x8 a1 = *(const f16x8*)(&esh[1][ar][0] + ksl * 16 + 8 * hi);
      if ((ks & 1) == 0) {
#pragma unroll
        for (int q = 0; q < 4; ++q) {
          BB[q][0] = *(const f16x8*)(pBp[q][0] + (size_t)ksn * 512);
          BB[q][1] = *(const f16x8*)(pBp[q][1] + (size_t)ksn * 512);
        }
#pragma unroll
        for (int q = 0; q < 4; ++q) {
          accH[q] = MFMA16(a0, BA[q][0], accH[q]);
          accL[q] = MFMA16(a0, BA[q][1], accL[q]);
          accL[q] = MFMA16(a1, BA[q][0], accL[q]);
        }
      } else {
#pragma unroll
        for (int q = 0; q < 4; ++q) {
          BA[q][0] = *(const f16x8*)(pBp[q][0] + (size_t)ksn * 512);
          BA[q][1] = *(const f16x8*)(pBp[q][1] + (size_t)ksn * 512);
        }
#pragma unroll
        for (int q = 0; q < 4; ++q) {
          accH[q] = MFMA16(a0, BB[q][0], accH[q]);
          accL[q] = MFMA16(a0, BB[q][1], accL[q]);
          accL[q] = MFMA16(a1, BB[q][0], accL[q]);
        }
      }
    }
  }

#pragma unroll
  for (int r = 0; r < 16; ++r) {
    float bs = accH[0][r] + accL[0][r] * INV2048 - hnv[0];
    int   bj = (jg * 4 + 0) * 32 + lo;
#pragma unroll
    for (int q = 1; q < 4; ++q) {
      const float s = accH[q][r] + accL[q][r] * INV2048 - hnv[q];
      const int   j = (jg * 4 + q) * 32 + lo;
      if (s > bs) { bs = s; bj = j; }
    }
#pragma unroll
    for (int d = 1; d < 32; d <<= 1) {
      const float os = __shfl_xor(bs, d, 64);
      const int   oj = __shfl_xor(bj, d, 64);
      if (os > bs || (os == bs && oj < bj)) { bs = os; bj = oj; }
    }
    if (lo == 0) {
      const int wloc = m * 32 + (r & 3) + 8 * (r >> 2) + 4 * hi;
      scs[jg][wloc] = bs; scj[jg][wloc] = bj;
    }
  }
  __syncthreads();
  if (tid < 64) {
    float bs = scs[0][tid]; int bj = scj[0][tid];
#pragma unroll
    for (int g = 1; g < 4; ++g) {
      const float s = scs[g][tid]; const int j = scj[g][tid];
      if (s > bs || (s == bs && j < bj)) { bs = s; bj = j; }
    }
    bestj[tid] = bj;
  }
  __syncthreads();
  {
    const int rr = tid >> 6;
    const int c4 = (tid & 63) * 4;
#pragma unroll
    for (int pass = 0; pass < 8; ++pass) {
      const int r = pass * 8 + rr;
      const int jb = bestj[r];
      const float4 v = *(const float4*)(cbk + (size_t)jb * EE + c4);
      *(float4*)(out + (size_t)(w0 + r) * EE + c4) = v;
    }
  }
}

// ================= fallback: R1 fused VALU kernel (known-good) =================
#define V 8
#define LAGS 4
#define WIN 64
#define STEP 16
#define CONV_OUT 16
#define WPB 16
#define TPB 256
#define NWORD 19
#define YSTRIDE 80
#define XSPAN 304
#define FOFF_YS   0
#define FOFF_XS   10240
#define FOFF_ES   10240
#define FOFF_SC   0
#define FOFF_SI   4096
#define FOFF_PS   8192
#define FOFF_PI   8448
#define FOFF_IW   8704
#define SMEM_FLOATS 14336

__device__ __forceinline__ float f4get(const float4& v, int i) {
  return i == 0 ? v.x : (i == 1 ? v.y : (i == 2 ? v.z : v.w));
}

__device__ __forceinline__ float conv_one(const float* xs, int p, const float4* cw, float cb0) {
  float a = cb0;
#pragma unroll
  for (int v = 0; v < V; ++v) {
    const float4 xv = *(const float4*)(xs + v * XSPAN + 4 * p);
    a = fmaf(xv.x, cw[v].x, a);
    a = fmaf(xv.y, cw[v].y, a);
    a = fmaf(xv.z, cw[v].z, a);
    a = fmaf(xv.w, cw[v].w, a);
  }
  return fmaxf(a, 0.0f);
}

__global__ __launch_bounds__(TPB, 2)
void tok_fused(const float* __restrict__ x, const float* __restrict__ conv_w,
               const float* __restrict__ conv_b, const float* __restrict__ lin_w,
               const float* __restrict__ lin_b, const float* __restrict__ cbk,
               float* __restrict__ out)
{
  __shared__ float smem[SMEM_FLOATS];
  float* ys = smem + FOFF_YS;
  float* xs = smem + FOFF_XS;
  float* es = smem + FOFF_ES;
  float* sc = smem + FOFF_SC;
  int*   si = (int*)(smem + FOFF_SI);
  float* ps = smem + FOFF_PS;
  int*   pi = (int*)(smem + FOFF_PI);
  int*   iw = (int*)(smem + FOFF_IW);
  const int tid = threadIdx.x;
  const int b   = blockIdx.x >> 5;
  const int t0  = (blockIdx.x & 31) * WPB;
  const float* xb = x + (size_t)b * V * SSN + (size_t)t0 * STEP;
#pragma unroll
  for (int v = 0; v < V; ++v)
    for (int j = tid; j < XSPAN; j += TPB)
      xs[v * XSPAN + j] = xb[(size_t)v * SSN + j];
  double accd[WPB];
#pragma unroll
  for (int w = 0; w < WPB; ++w) accd[w] = 0.0;
  for (int half = 0; half < 2; ++half) {
    __syncthreads();
    {
      const int ep  = half * 128 + (tid >> 1);
      const int row = ep & 127;
      float4 cw[V];
      const float4* cwp = (const float4*)(conv_w + (size_t)ep * (V * LAGS));
#pragma unroll
      for (int v = 0; v < V; ++v) cw[v] = cwp[v];
      const float cb0 = conv_b[ep];
      const int c0 = (tid & 1) ? 10 : 0;
      const int c1 = (tid & 1) ? NWORD : 10;
      for (int c = c0; c < c1; ++c) {
        const int p = 4 * c;
        float r0 = conv_one(xs, p + 0, cw, cb0);
        float r1 = conv_one(xs, p + 1, cw, cb0);
        float r2 = conv_one(xs, p + 2, cw, cb0);
        float r3 = conv_one(xs, p + 3, cw, cb0);
        *(float4*)(ys + row * YSTRIDE + 4 * c) = make_float4(r0, r1, r2, r3);
      }
    }
    __syncthreads();
    const float* lwbase = lin_w + (size_t)tid * (EE * CONV_OUT) + half * (128 * CONV_OUT);
    float4 nA, nB, nC, nD;
    {
      const float4* p4 = (const float4*)(lwbase);
      nA = p4[0]; nB = p4[1]; nC = p4[2]; nD = p4[3];
    }
    for (int er = 0; er < 128; ++er) {
      const float4 lA = nA, lB = nB, lC = nC, lD = nD;
      const int ern = (er + 1) & 127;
      {
        const float4* p4 = (const float4*)(lwbase + ern * CONV_OUT);
        nA = p4[0]; nB = p4[1]; nC = p4[2]; nD = p4[3];
      }
      float4 yr[NWORD];
      const float4* yp = (const float4*)(ys + er * YSTRIDE);
#pragma unroll
      for (int q = 0; q < NWORD; ++q) yr[q] = yp[q];
      float it[WPB];
#pragma unroll
      for (int w = 0; w < WPB; ++w) it[w] = 0.0f;
#pragma unroll
      for (int o = 0; o < CONV_OUT; ++o) {
        const float lw_o = f4get(o < 4 ? lA : (o < 8 ? lB : (o < 12 ? lC : lD)), o & 3);
#pragma unroll
        for (int w = 0; w < WPB; ++w) {
          const int p = 4 * w + o;
          it[w] = fmaf(lw_o, f4get(yr[p >> 2], p & 3), it[w]);
        }
      }
#pragma unroll
      for (int w = 0; w < WPB; ++w) accd[w] += (double)it[w];
    }
  }
#pragma unroll
  for (int w = 0; w < WPB; ++w)
    es[w * EE + tid] = (float)accd[w] + lin_b[tid];
  __syncthreads();
  float s_best[WPB];
  int   i_best[WPB];
#pragma unroll
  for (int jj = 0; jj < 2; ++jj) {
    const int j = tid + jj * 256;
    const float4* cbp = (const float4*)(cbk + (size_t)j * EE);
    double sdd[WPB];
    float  sd32[WPB];
#pragma unroll
    for (int w = 0; w < WPB; ++w) { sdd[w] = 0.0; sd32[w] = 0.f; }
    double ndd = 0.0;
    float  nd32 = 0.f;
    float4 c4n = cbp[0];
    for (int i16 = 0; i16 < 4; ++i16) {
      for (int i4i = 0; i4i < 16; ++i4i) {
        const int i4 = i16 * 16 + i4i;
        const float4 c4 = c4n;
        c4n = cbp[(i4 + 1 <= 63) ? (i4 + 1) : 63];
        nd32 = fmaf(c4.x, c4.x, nd32);
        nd32 = fmaf(c4.y, c4.y, nd32);
        nd32 = fmaf(c4.z, c4.z, nd32);
        nd32 = fmaf(c4.w, c4.w, nd32);
#pragma unroll
        for (int w = 0; w < WPB; ++w) {
          const float4 e4 = *(const float4*)(es + w * EE + i4 * 4);
          sd32[w] = fmaf(c4.x, e4.x, sd32[w]);
          sd32[w] = fmaf(c4.y, e4.y, sd32[w]);
          sd32[w] = fmaf(c4.z, e4.z, sd32[w]);
          sd32[w] = fmaf(c4.w, e4.w, sd32[w]);
        }
      }
#pragma unroll
      for (int w = 0; w < WPB; ++w) { sdd[w] += (double)sd32[w]; sd32[w] = 0.f; }
      ndd += (double)nd32; nd32 = 0.f;
    }
#pragma unroll
    for (int w = 0; w < WPB; ++w) {
      const float s = (float)(sdd[w] - 0.5 * ndd);
      if (jj == 0) { s_best[w] = s; i_best[w] = j; }
      else if (s > s_best[w]) { s_best[w] = s; i_best[w] = j; }
    }
  }
#pragma unroll
  for (int w = 0; w < WPB; ++w) {
    sc[w * EE + tid] = s_best[w];
    si[w * EE + tid] = i_best[w];
  }
  __syncthreads();
  {
    const int w = tid >> 4, seg = tid & 15;
    float mm = -INFINITY; int mi = 0x7fffffff;
    for (int t = seg * 16; t < seg * 16 + 16; ++t) {
      const float s = sc[w * EE + t];
      const int   jx = si[w * EE + t];
      if (s > mm || (s == mm && jx < mi)) { mm = s; mi = jx; }
    }
    ps[w * 16 + seg] = mm; pi[w * 16 + seg] = mi;
  }
  __syncthreads();
  if (tid < WPB) {
    const int w = tid;
    float mm = -INFINITY; int mi = 0x7fffffff;
    for (int t = 0; t < 16; ++t) {
      const float s = ps[w * 16 + t];
      const int   jx = pi[w * 16 + t];
      if (s > mm || (s == mm && jx < mi)) { mm = s; mi = jx; }
    }
    iw[w] = mi;
  }
  __syncthreads();
  const size_t outb = ((size_t)b * TTOT + t0) * EE;
#pragma unroll
  for (int w = 0; w < WPB; ++w)
    out[outb + (size_t)w * EE + tid] = cbk[(size_t)iw[w] * EE + tid];
}

// ================= launch =================
extern "C" void kernel_launch(void* const* d_in, const int* in_sizes, int n_in,
                              void* d_out, int out_size, void* d_ws, size_t ws_size,
                              hipStream_t stream) {
  const float* x      = (const float*)d_in[0];
  const float* conv_w = (const float*)d_in[1];
  const float* conv_b = (const float*)d_in[2];
  const float* lin_w  = (const float*)d_in[3];
  const float* lin_b  = (const float*)d_in[4];
  const float* cbk    = (const float*)d_in[5];
  float* out = (float*)d_out;

  if (ws_size < WS_NEED) {
    tok_fused<<<dim3(32 * 32), dim3(TPB), 0, stream>>>(x, conv_w, conv_b, lin_w, lin_b, cbk, out);
    return;
  }
  char* ws = (char*)d_ws;
  f16*   y0   = (f16*)(ws + OFF_Y0);
  f16*   y1   = (f16*)(ws + OFF_Y1);
  f16*   lwp0 = (f16*)(ws + OFF_LW0);
  f16*   lwp1 = (f16*)(ws + OFF_LW1);
  f16*   cbp0 = (f16*)(ws + OFF_CB0);
  f16*   cbp1 = (f16*)(ws + OFF_CB1);
  float* hn   = (float*)(ws + OFF_HN);

  k01<<<848, 256, 0, stream>>>(lin_w, cbk, lwp0, lwp1, cbp0, cbp1, hn,
                               x, conv_w, conv_b, y0, y1);

  if (ws_size >= WS_NEED2) {
    float* pacc0 = (float*)(ws + OFF_E0);
    float* pacc1 = (float*)(ws + OFF_P1);
    k2p<<<512, 512, 0, stream>>>(y0, y1, lwp0, lwp1, pacc0, pacc1);
    k3s<<<256, 512, 0, stream>>>(pacc0, pacc1, lin_b, cbp0, cbp1, hn, cbk, out);
  } else {
    f16* e0 = (f16*)(ws + OFF_E0);
    f16* e1 = (f16*)(ws + OFF_E1);
    k2_linear<<<256, 512, 0, stream>>>(y0, y1, lwp0, lwp1, lin_b, e0, e1);
    k3_old<<<256, 512, 0, stream>>>(e0, e1, cbp0, cbp1, hn, cbk, out);
  }
}

// Round 13
// 196.403 us; speedup vs baseline: 1.3868x; 1.2860x over previous
//
#include <hip/hip_runtime.h>

typedef _Float16 f16;
typedef _Float16 f16x4 __attribute__((ext_vector_type(4)));
typedef _Float16 f16x8 __attribute__((ext_vector_type(8)));
typedef float    f32x16 __attribute__((ext_vector_type(16)));

#define NB 32
#define TTOT 512
#define SSN 8256
#define PT 2064
#define EE 256
#define KCB 512

// ---------------- ws layout (bytes) ----------------
#define YB   ((size_t)NB*EE*PT*2)
#define LWB  ((size_t)EE*4096*2)
#define CBB  ((size_t)KCB*EE*2)
#define EBB  ((size_t)16384*EE*2)
#define OFF_Y0  ((size_t)0)
#define OFF_Y1  (YB)
#define OFF_LW0 (2*YB)
#define OFF_LW1 (2*YB + LWB)
#define OFF_CB0 (2*YB + 2*LWB)
#define OFF_CB1 (2*YB + 2*LWB + CBB)
#define OFF_HN  (2*YB + 2*LWB + 2*CBB)
#define OFF_E0  (OFF_HN + 4096)            // middle path: eh0 | split path: pacc0
#define OFF_E1  (OFF_E0 + EBB)
#define WS_NEED (OFF_E1 + EBB)             // 89.1 MB (middle path)
#define PACC_BYTES ((size_t)16384*EE*4)    // 16.78 MB
#define OFF_P1  (WS_NEED)                  // split path: pacc1
#define WS_NEED2 (WS_NEED + PACC_BYTES)    // 105.9 MB

#define INV2048 4.8828125e-4f

struct h2 { f16 hi, lo; };
__device__ __forceinline__ h2 split2(float v) {
  h2 r;
  r.hi = (f16)v;
  r.lo = (f16)((v - (float)r.hi) * 2048.0f);
  return r;
}

__device__ __forceinline__ f16x8 ldsfrag(const f16* p) {
  union { f16x8 v8; f16x4 v4[2]; } u;
  u.v4[0] = *(const f16x4*)p;
  u.v4[1] = *(const f16x4*)(p + 4);
  return u.v8;
}

#define MFMA16(a,b,c) __builtin_amdgcn_mfma_f32_32x32x16_f16(a, b, c, 0, 0, 0)

// ================= k01: fused repack (k0) + conv (k1) =================
__global__ __launch_bounds__(256, 2)
void k01(const float* __restrict__ lin_w, const float* __restrict__ cbk,
         f16* __restrict__ lwp0, f16* __restrict__ lwp1,
         f16* __restrict__ cbp0, f16* __restrict__ cbp1, float* __restrict__ hn,
         const float* __restrict__ x, const float* __restrict__ cw,
         const float* __restrict__ cb, f16* __restrict__ y0, f16* __restrict__ y1)
{
  __shared__ float part[4][32];
  const int tid = threadIdx.x;
  const int bix = blockIdx.x;
  if (bix < 272) {
    const int bid = bix;
    if (bid < 256) {
      const int eo = bid, nb = eo >> 5, lo = eo & 31;
      const int ep = tid;
      const float* src = lin_w + (size_t)eo * 4096 + ep * 16;
      float f[16];
      *(float4*)(f + 0)  = ((const float4*)src)[0];
      *(float4*)(f + 4)  = ((const float4*)src)[1];
      *(float4*)(f + 8)  = ((const float4*)src)[2];
      *(float4*)(f + 12) = ((const float4*)src)[3];
      union { f16x8 v; f16 e[8]; } a0, a1, b0, b1;
#pragma unroll
      for (int i = 0; i < 8; ++i) {
        { h2 s = split2(f[i]);     a0.e[i] = s.hi; a1.e[i] = s.lo; }
        { h2 s = split2(f[i + 8]); b0.e[i] = s.hi; b1.e[i] = s.lo; }
      }
      const size_t base = ((size_t)nb * 16384 + (size_t)ep * 64 + lo) * 8;
      *(f16x8*)(lwp0 + base)       = a0.v;   // lane hi=0 slot
      *(f16x8*)(lwp0 + base + 256) = b0.v;   // lane hi=1 slot
      *(f16x8*)(lwp1 + base)       = a1.v;
      *(f16x8*)(lwp1 + base + 256) = b1.v;
    } else {
      const int jb = bid - 256;              // 0..15
      const int lane = tid & 63, ksg = tid >> 6;
      const int hi = lane >> 5, lo = lane & 31;
      const int j = jb * 32 + lo;
      float s = 0.f;
#pragma unroll
      for (int kq = 0; kq < 4; ++kq) {
        const int ks = ksg * 4 + kq;
        const float* src = cbk + (size_t)j * 256 + ks * 16 + 8 * hi;
        float f[8];
        *(float4*)(f + 0) = ((const float4*)src)[0];
        *(float4*)(f + 4) = ((const float4*)src)[1];
        union { f16x8 v; f16 e[8]; } h0, h1;
#pragma unroll
        for (int i = 0; i < 8; ++i) {
          s = fmaf(f[i], f[i], s);
          h2 t = split2(f[i]); h0.e[i] = t.hi; h1.e[i] = t.lo;
        }
        const size_t base = ((size_t)jb * 1024 + (size_t)ks * 64 + lane) * 8;
        *(f16x8*)(cbp0 + base) = h0.v;
        *(f16x8*)(cbp1 + base) = h1.v;
      }
      s += __shfl_xor(s, 32, 64);            // fold hi=0/1
      if (lane < 32) part[ksg][lane] = s;
      __syncthreads();
      if (tid < 32)
        hn[jb * 32 + tid] = 0.5f * (part[0][tid] + part[1][tid] + part[2][tid] + part[3][tid]);
    }
  } else {
    const int bid = bix - 272;               // 0..575
    const int b = bid / 18, rem = bid % 18;
    const int eq = rem / 9, ptile = rem % 9;
    const int p = ptile * 256 + tid;
    const bool valid = p < PT;
    const int pc = valid ? p : (PT - 1);
    float4 xv[8];
#pragma unroll
    for (int v = 0; v < 8; ++v)
      xv[v] = *(const float4*)(x + ((size_t)b * 8 + v) * SSN + 4 * pc);
    const int e0 = eq * 128;
    float4 wc[8], wn[8];
#pragma unroll
    for (int v = 0; v < 8; ++v) wc[v] = *(const float4*)(cw + (size_t)e0 * 32 + v * 4);
    for (int ep = e0; ep < e0 + 128; ++ep) {
      const int epn = (ep + 1 < e0 + 128) ? ep + 1 : ep;
#pragma unroll
      for (int v = 0; v < 8; ++v) wn[v] = *(const float4*)(cw + (size_t)epn * 32 + v * 4);
      float a = cb[ep];
#pragma unroll
      for (int v = 0; v < 8; ++v) {
        a = fmaf(xv[v].x, wc[v].x, a);
        a = fmaf(xv[v].y, wc[v].y, a);
        a = fmaf(xv[v].z, wc[v].z, a);
        a = fmaf(xv[v].w, wc[v].w, a);
      }
      a = fmaxf(a, 0.f);
      if (valid) {
        const h2 s = split2(a);
        const size_t o = ((size_t)b * EE + ep) * PT + p;
        y0[o] = s.hi; y1[o] = s.lo;
      }
#pragma unroll
      for (int v = 0; v < 8; ++v) wc[v] = wn[v];
    }
  }
}

// ====== k2ps: linear GEMM, K-split-2, R10 geometry (no-spill proven) ==========
// 512 blocks = 2 kh(K=2048) x 64 M-tiles(256w) x 4 N-quarters(64eo); 256 thr = 4 waves.
// Wave-tile 64x64 (R=1.5). LDS 66KB -> 2 blocks/CU, 2 waves/SIMD; 1 barrier/ss.
__global__ __launch_bounds__(256, 2)
void k2ps(const f16* __restrict__ yh0, const f16* __restrict__ yh1,
          const f16* __restrict__ lwp0, const f16* __restrict__ lwp1,
          float* __restrict__ pacc0, float* __restrict__ pacc1)
{
  __shared__ __align__(16) f16 ysh[2][2][4][1040];   // [buf][limb][ke][pos] 33.3KB
  __shared__ __align__(16) f16 bsh[2][4][2][2][512]; // [buf][ke][nb][limb][frag] 32KB
  const int tid = threadIdx.x;
  // XCD-aware swizzle over 512 blocks (bijective: 512 % 8 == 0)
  const int sw = (blockIdx.x & 7) * 64 + (blockIdx.x >> 3);
  const int kh = sw >> 8;                  // K-half
  const int rest = sw & 255;
  const int mt = rest >> 2, nq = rest & 3; // 64 M-tiles x 4 N-quarters
  const int b  = mt >> 1;
  const int p4 = (mt & 1) * 1024;          // position offset (4 * t0)
  const int lane = tid & 63, wv = tid >> 6;   // 4 waves, mg = wv
  const int mg = wv;
  const int hi = lane >> 5, lo = lane & 31;

  // B staging: wave wv stages ke=wv (frag ep = kh*128 + ss*4 + wv), nb {0,1} x limb {0,1}
  const f16* pB0 = lwp0 + ((size_t)(nq * 2) * 256 + kh * 128 + wv) * 512 + lane * 8;
  const f16* pB1 = lwp1 + ((size_t)(nq * 2) * 256 + kh * 128 + wv) * 512 + lane * 8;
  // y staging: wave wv stages rows r=2wv, 2wv+1 (same limb, ke and ke+1); 1040 f16 each
  const f16* pY0 = ((wv >> 1) ? yh1 : yh0)
                   + ((size_t)b * EE + kh * 128 + ((wv * 2) & 3)) * PT + p4 + lane * 8;
  const bool yext = lane < 2;

  f32x16 accH[2][2], accL[2][2];
#pragma unroll
  for (int m2 = 0; m2 < 2; ++m2)
#pragma unroll
    for (int n2 = 0; n2 < 2; ++n2)
#pragma unroll
      for (int r = 0; r < 16; ++r) { accH[m2][n2][r] = 0.f; accL[m2][n2][r] = 0.f; }

  float4 br[4], ya[2][2], ye[2];

#define K2LOAD(ss_) do {                                                       \
    const size_t bo = (size_t)(ss_) * 2048;                                    \
    br[0] = *(const float4*)(pB0 + bo);                                        \
    br[1] = *(const float4*)(pB1 + bo);                                        \
    br[2] = *(const float4*)(pB0 + 131072 + bo);                               \
    br[3] = *(const float4*)(pB1 + 131072 + bo);                               \
    const size_t yo = (size_t)(ss_) * (4 * PT);                                \
    _Pragma("unroll")                                                          \
    for (int j = 0; j < 2; ++j) {                                              \
      const f16* ysj = pY0 + (size_t)j * PT + yo;                              \
      ya[j][0] = *(const float4*)(ysj);                                        \
      ya[j][1] = *(const float4*)(ysj + 512);                                  \
      if (yext) ye[j] = *(const float4*)(ysj + 1024);                          \
    }                                                                          \
  } while (0)

#define K2WRITE(bb_) do {                                                      \
    *(float4*)&bsh[bb_][wv][0][0][lane * 8] = br[0];                           \
    *(float4*)&bsh[bb_][wv][0][1][lane * 8] = br[1];                           \
    *(float4*)&bsh[bb_][wv][1][0][lane * 8] = br[2];                           \
    *(float4*)&bsh[bb_][wv][1][1][lane * 8] = br[3];                           \
    _Pragma("unroll")                                                          \
    for (int j = 0; j < 2; ++j) {                                              \
      const int r = wv * 2 + j;                                                \
      f16* yd = &ysh[bb_][r >> 2][r & 3][lane * 8];                            \
      *(float4*)yd = ya[j][0];                                                 \
      *(float4*)(yd + 512) = ya[j][1];                                         \
      if (yext) *(float4*)(yd + 1024) = ye[j];                                 \
    }                                                                          \
  } while (0)

  // prologue: tile 0 -> buf0
  K2LOAD(0);
  K2WRITE(0);
  __syncthreads();

  for (int ss = 0; ss < 32; ++ss) {
    const int cur = ss & 1;
    K2LOAD((ss < 31) ? ss + 1 : 31);   // issue loads early; consumed after MFMA

    // MFMA on buf[cur]
#pragma unroll
    for (int ke = 0; ke < 4; ++ke) {
      f16x8 a[2][2], bbf[2][2];
#pragma unroll
      for (int m2 = 0; m2 < 2; ++m2) {
        const int aoff = 4 * (mg * 64 + m2 * 32 + lo) + 8 * hi;
        a[m2][0] = ldsfrag(&ysh[cur][0][ke][aoff]);
        a[m2][1] = ldsfrag(&ysh[cur][1][ke][aoff]);
      }
#pragma unroll
      for (int n2 = 0; n2 < 2; ++n2) {
        bbf[n2][0] = *(const f16x8*)&bsh[cur][ke][n2][0][lane * 8];
        bbf[n2][1] = *(const f16x8*)&bsh[cur][ke][n2][1][lane * 8];
      }
#pragma unroll
      for (int m2 = 0; m2 < 2; ++m2)
#pragma unroll
        for (int n2 = 0; n2 < 2; ++n2) {
          accH[m2][n2] = MFMA16(a[m2][0], bbf[n2][0], accH[m2][n2]);
          accL[m2][n2] = MFMA16(a[m2][0], bbf[n2][1], accL[m2][n2]);
          accL[m2][n2] = MFMA16(a[m2][1], bbf[n2][0], accL[m2][n2]);
        }
    }

    K2WRITE(cur ^ 1);    // staged regs die here
    __syncthreads();
  }
#undef K2LOAD
#undef K2WRITE

  // epilogue: partial v = accH + accL/2048 -> plain store into own kh buffer
  float* pacc = kh ? pacc1 : pacc0;
#pragma unroll
  for (int m2 = 0; m2 < 2; ++m2)
#pragma unroll
    for (int n2 = 0; n2 < 2; ++n2) {
      const int eo = nq * 64 + n2 * 32 + lo;
#pragma unroll
      for (int r = 0; r < 16; ++r) {
        const int wloc = mg * 64 + m2 * 32 + (r & 3) + 8 * (r >> 2) + 4 * hi;
        pacc[(size_t)(mt * 256 + wloc) * EE + eo] =
            accH[m2][n2][r] + accL[m2][n2][r] * INV2048;
      }
    }
}

// ============ k3s: combine(pacc0+pacc1+bias) + distance MFMA + argmax =========
__global__ __launch_bounds__(512, 1)
void k3s(const float* __restrict__ pacc0, const float* __restrict__ pacc1,
         const float* __restrict__ lin_b,
         const f16* __restrict__ cbp0, const f16* __restrict__ cbp1,
         const float* __restrict__ hn, const float* __restrict__ cbk,
         float* __restrict__ out)
{
  __shared__ __align__(16) f16 esh[2][64][136];   // [limb][w][k-half]
  __shared__ float scs[4][64];
  __shared__ int   scj[4][64];
  __shared__ int   bestj[64];
  const int tid = threadIdx.x;
  const int w0 = blockIdx.x * 64;
  const int lane = tid & 63, wv = tid >> 6;
  const int m = wv & 1, jg = wv >> 1;
  const int hi = lane >> 5, lo = lane & 31;

  const f16* pBp[4][2];
  float hnv[4];
#pragma unroll
  for (int q = 0; q < 4; ++q) {
    const int jb = jg * 4 + q;
    pBp[q][0] = cbp0 + ((size_t)jb * 1024 + lane) * 8;
    pBp[q][1] = cbp1 + ((size_t)jb * 1024 + lane) * 8;
    hnv[q] = hn[jb * 32 + lo];
  }
  f32x16 accH[4], accL[4];
#pragma unroll
  for (int q = 0; q < 4; ++q)
#pragma unroll
    for (int r = 0; r < 16; ++r) { accH[q][r] = 0.f; accL[q][r] = 0.f; }

  const int ar = m * 32 + lo;
  f16x8 BA[4][2], BB[4][2];
#pragma unroll
  for (int q = 0; q < 4; ++q) {
    BA[q][0] = *(const f16x8*)(pBp[q][0]);
    BA[q][1] = *(const f16x8*)(pBp[q][1]);
  }

  for (int kh = 0; kh < 2; ++kh) {
    if (kh) __syncthreads();
    { // stage e-half = pacc0 + pacc1 + bias; split to limbs in LDS
      const int r = tid >> 3, c8 = tid & 7;
      const size_t idx = (size_t)(w0 + r) * EE + kh * 128 + c8 * 16;
      const float* ps0 = pacc0 + idx;
      const float* ps1 = pacc1 + idx;
      const float* bsp = lin_b + kh * 128 + c8 * 16;
      float f[16];
#pragma unroll
      for (int i = 0; i < 4; ++i) {
        const float4 v0 = ((const float4*)ps0)[i];
        const float4 v1 = ((const float4*)ps1)[i];
        const float4 bb = ((const float4*)bsp)[i];
        f[4 * i + 0] = v0.x + v1.x + bb.x;
        f[4 * i + 1] = v0.y + v1.y + bb.y;
        f[4 * i + 2] = v0.z + v1.z + bb.z;
        f[4 * i + 3] = v0.w + v1.w + bb.w;
      }
      union { f16x8 v; f16 e[8]; } h0[2], h1[2];
#pragma unroll
      for (int i = 0; i < 16; ++i) {
        const h2 s = split2(f[i]);
        h0[i >> 3].e[i & 7] = s.hi;
        h1[i >> 3].e[i & 7] = s.lo;
      }
      *(f16x8*)&esh[0][r][c8 * 16]     = h0[0].v;
      *(f16x8*)&esh[0][r][c8 * 16 + 8] = h0[1].v;
      *(f16x8*)&esh[1][r][c8 * 16]     = h1[0].v;
      *(f16x8*)&esh[1][r][c8 * 16 + 8] = h1[1].v;
    }
    __syncthreads();
#pragma unroll
    for (int ksl = 0; ksl < 8; ++ksl) {
      const int ks = kh * 8 + ksl;
      const int ksn = (ks < 15) ? ks + 1 : 15;
      const f16x8 a0 = *(const f16x8*)(&esh[0][ar][0] + ksl * 16 + 8 * hi);
      const f16x8 a1 = *(const f16x8*)(&esh[1][ar][0] + ksl * 16 + 8 * hi);
      if ((ks & 1) == 0) {
#pragma unroll
        for (int q = 0; q < 4; ++q) {
          BB[q][0] = *(const f16x8*)(pBp[q][0] + (size_t)ksn * 512);
          BB[q][1] = *(const f16x8*)(pBp[q][1] + (size_t)ksn * 512);
        }
#pragma unroll
        for (int q = 0; q < 4; ++q) {
          accH[q] = MFMA16(a0, BA[q][0], accH[q]);
          accL[q] = MFMA16(a0, BA[q][1], accL[q]);
          accL[q] = MFMA16(a1, BA[q][0], accL[q]);
        }
      } else {
#pragma unroll
        for (int q = 0; q < 4; ++q) {
          BA[q][0] = *(const f16x8*)(pBp[q][0] + (size_t)ksn * 512);
          BA[q][1] = *(const f16x8*)(pBp[q][1] + (size_t)ksn * 512);
        }
#pragma unroll
        for (int q = 0; q < 4; ++q) {
          accH[q] = MFMA16(a0, BB[q][0], accH[q]);
          accL[q] = MFMA16(a0, BB[q][1], accL[q]);
          accL[q] = MFMA16(a1, BB[q][0], accL[q]);
        }
      }
    }
  }

  // per-w argmax over j (min-index tie-break)
#pragma unroll
  for (int r = 0; r < 16; ++r) {
    float bs = accH[0][r] + accL[0][r] * INV2048 - hnv[0];
    int   bj = (jg * 4 + 0) * 32 + lo;
#pragma unroll
    for (int q = 1; q < 4; ++q) {
      const float s = accH[q][r] + accL[q][r] * INV2048 - hnv[q];
      const int   j = (jg * 4 + q) * 32 + lo;
      if (s > bs) { bs = s; bj = j; }   // ascending j: strict > keeps lowest
    }
#pragma unroll
    for (int d = 1; d < 32; d <<= 1) {
      const float os = __shfl_xor(bs, d, 64);
      const int   oj = __shfl_xor(bj, d, 64);
      if (os > bs || (os == bs && oj < bj)) { bs = os; bj = oj; }
    }
    if (lo == 0) {
      const int wloc = m * 32 + (r & 3) + 8 * (r >> 2) + 4 * hi;
      scs[jg][wloc] = bs; scj[jg][wloc] = bj;
    }
  }
  __syncthreads();
  if (tid < 64) {
    float bs = scs[0][tid]; int bj = scj[0][tid];
#pragma unroll
    for (int g = 1; g < 4; ++g) {
      const float s = scs[g][tid]; const int j = scj[g][tid];
      if (s > bs || (s == bs && j < bj)) { bs = s; bj = j; }
    }
    bestj[tid] = bj;
  }
  __syncthreads();
  { // gather codebook rows to output
    const int rr = tid >> 6;
    const int c4 = (tid & 63) * 4;
#pragma unroll
    for (int pass = 0; pass < 8; ++pass) {
      const int r = pass * 8 + rr;
      const int jb = bestj[r];
      const float4 v = *(const float4*)(cbk + (size_t)jb * EE + c4);
      *(float4*)(out + (size_t)(w0 + r) * EE + c4) = v;
    }
  }
}

// ======== middle path (ws < WS_NEED2): R7-proven k2 (eh limbs) + k3_old =======
__global__ __launch_bounds__(512, 1)
void k2_linear(const f16* __restrict__ yh0, const f16* __restrict__ yh1,
               const f16* __restrict__ lwp0, const f16* __restrict__ lwp1,
               const float* __restrict__ lin_b,
               f16* __restrict__ eh0, f16* __restrict__ eh1)
{
  __shared__ __align__(16) f16 ysh[2][2][4][528];       // [buf][limb][ke][pos]
  __shared__ __align__(16) f16 bsh[2][4][4][2][512];    // [buf][ke][nb][limb][frag]
  const int tid = threadIdx.x;
  const int sw = (blockIdx.x & 7) * 32 + (blockIdx.x >> 3);
  const int nh = sw >> 7, mt = sw & 127;
  const int b = mt >> 2;
  const int p0 = (mt & 3) * 512;
  const int lane = tid & 63, wv = tid >> 6;
  const int m = wv >> 1, nq = wv & 1;
  const int hi = lane >> 5, lo = lane & 31;
  const int aoff = 4 * (m * 32 + lo) + 8 * hi;

  const int bke = wv >> 1;
  const int bnb0 = (wv & 1) * 2;
  const f16* bs[2][2];
#pragma unroll
  for (int j = 0; j < 2; ++j) {
    bs[j][0] = lwp0 + ((size_t)(nh * 4 + bnb0 + j) * 256) * 512 + lane * 8;
    bs[j][1] = lwp1 + ((size_t)(nh * 4 + bnb0 + j) * 256) * 512 + lane * 8;
  }
  const int ylimb = wv >> 2, yke = wv & 3;
  const f16* ysrcp = ylimb ? yh1 : yh0;
  const size_t ybase0 = ((size_t)b * EE + yke) * PT + p0 + lane * 8;

  f32x16 accH[2], accL[2];
#pragma unroll
  for (int n = 0; n < 2; ++n)
#pragma unroll
    for (int r = 0; r < 16; ++r) { accH[n][r] = 0.f; accL[n][r] = 0.f; }

  { // prologue: stage ss=0 into buf0
    const size_t epo = (size_t)bke * 512;
    float4 br[4];
#pragma unroll
    for (int i = 0; i < 4; ++i) br[i] = *(const float4*)(bs[i >> 1][i & 1] + epo);
    const float4 ya = *(const float4*)(ysrcp + ybase0);
    float4 yb{};
    if (lane < 2) yb = *(const float4*)(ysrcp + ybase0 + 512);
#pragma unroll
    for (int i = 0; i < 4; ++i)
      *(float4*)&bsh[0][bke][bnb0 + (i >> 1)][i & 1][lane * 8] = br[i];
    f16* yd = &ysh[0][ylimb][yke][lane * 8];
    *(float4*)yd = ya;
    if (lane < 2) *(float4*)(yd + 512) = yb;
  }
  __syncthreads();

  for (int ss = 0; ss < 64; ++ss) {
    const int cur = ss & 1;
    const int ssn = (ss < 63) ? ss + 1 : 63;
    const size_t epo = (size_t)(ssn * 4 + bke) * 512;
    float4 br[4];
#pragma unroll
    for (int i = 0; i < 4; ++i) br[i] = *(const float4*)(bs[i >> 1][i & 1] + epo);
    const size_t yb0 = ybase0 + (size_t)ssn * 4 * PT;
    const float4 ya = *(const float4*)(ysrcp + yb0);
    float4 yb{};
    if (lane < 2) yb = *(const float4*)(ysrcp + yb0 + 512);

#pragma unroll
    for (int ke = 0; ke < 4; ++ke) {
      const f16x8 a0 = ldsfrag(&ysh[cur][0][ke][aoff]);
      const f16x8 a1 = ldsfrag(&ysh[cur][1][ke][aoff]);
#pragma unroll
      for (int n = 0; n < 2; ++n) {
        const f16x8 b0 = *(const f16x8*)&bsh[cur][ke][nq * 2 + n][0][lane * 8];
        const f16x8 b1 = *(const f16x8*)&bsh[cur][ke][nq * 2 + n][1][lane * 8];
        accH[n] = MFMA16(a0, b0, accH[n]);
        accL[n] = MFMA16(a0, b1, accL[n]);
        accL[n] = MFMA16(a1, b0, accL[n]);
      }
    }
    {
      const int nxt = cur ^ 1;
#pragma unroll
      for (int i = 0; i < 4; ++i)
        *(float4*)&bsh[nxt][bke][bnb0 + (i >> 1)][i & 1][lane * 8] = br[i];
      f16* yd = &ysh[nxt][ylimb][yke][lane * 8];
      *(float4*)yd = ya;
      if (lane < 2) *(float4*)(yd + 512) = yb;
    }
    __syncthreads();
  }

#pragma unroll
  for (int n = 0; n < 2; ++n) {
    const int eo = nh * 128 + (nq * 2 + n) * 32 + lo;
    const float lb = lin_b[eo];
#pragma unroll
    for (int r = 0; r < 16; ++r) {
      const int wloc = m * 32 + (r & 3) + 8 * (r >> 2) + 4 * hi;
      const float v = accH[n][r] + accL[n][r] * INV2048 + lb;
      const h2 s = split2(v);
      const size_t o = (size_t)(mt * 128 + wloc) * EE + eo;
      eh0[o] = s.hi; eh1[o] = s.lo;
    }
  }
}

__global__ __launch_bounds__(512, 1)
void k3_old(const f16* __restrict__ eh0, const f16* __restrict__ eh1,
            const f16* __restrict__ cbp0, const f16* __restrict__ cbp1,
            const float* __restrict__ hn, const float* __restrict__ cbk,
            float* __restrict__ out)
{
  __shared__ __align__(16) f16 esh[2][64][136];
  __shared__ float scs[4][64];
  __shared__ int   scj[4][64];
  __shared__ int   bestj[64];
  const int tid = threadIdx.x;
  const int w0 = blockIdx.x * 64;
  const int lane = tid & 63, wv = tid >> 6;
  const int m = wv & 1, jg = wv >> 1;
  const int hi = lane >> 5, lo = lane & 31;

  const f16* pBp[4][2];
  float hnv[4];
#pragma unroll
  for (int q = 0; q < 4; ++q) {
    const int jb = jg * 4 + q;
    pBp[q][0] = cbp0 + ((size_t)jb * 1024 + lane) * 8;
    pBp[q][1] = cbp1 + ((size_t)jb * 1024 + lane) * 8;
    hnv[q] = hn[jb * 32 + lo];
  }
  f32x16 accH[4], accL[4];
#pragma unroll
  for (int q = 0; q < 4; ++q)
#pragma unroll
    for (int r = 0; r < 16; ++r) { accH[q][r] = 0.f; accL[q][r] = 0.f; }

  const int ar = m * 32 + lo;
  f16x8 BA[4][2], BB[4][2];
#pragma unroll
  for (int q = 0; q < 4; ++q) {
    BA[q][0] = *(const f16x8*)(pBp[q][0]);
    BA[q][1] = *(const f16x8*)(pBp[q][1]);
  }

  for (int kh = 0; kh < 2; ++kh) {
    if (kh) __syncthreads();
    {
      const int r = tid >> 3, c8 = tid & 7;
      const f16* s0 = eh0 + (size_t)(w0 + r) * EE + kh * 128;
      const f16* s1 = eh1 + (size_t)(w0 + r) * EE + kh * 128;
#pragma unroll
      for (int i = 0; i < 2; ++i) {
        const int c = (c8 * 2 + i) * 8;
        *(float4*)&esh[0][r][c] = *(const float4*)(s0 + c);
        *(float4*)&esh[1][r][c] = *(const float4*)(s1 + c);
      }
    }
    __syncthreads();
#pragma unroll
    for (int ksl = 0; ksl < 8; ++ksl) {
      const int ks = kh * 8 + ksl;
      const int ksn = (ks < 15) ? ks + 1 : 15;
      const f16x8 a0 = *(const f16x8*)(&esh[0][ar][0] + ksl * 16 + 8 * hi);
      const f16x8 a1 = *(const f16x8*)(&esh[1][ar][0] + ksl * 16 + 8 * hi);
      if ((ks & 1) == 0) {
#pragma unroll
        for (int q = 0; q < 4; ++q) {
          BB[q][0] = *(const f16x8*)(pBp[q][0] + (size_t)ksn * 512);
          BB[q][1] = *(const f16x8*)(pBp[q][1] + (size_t)ksn * 512);
        }
#pragma unroll
        for (int q = 0; q < 4; ++q) {
          accH[q] = MFMA16(a0, BA[q][0], accH[q]);
          accL[q] = MFMA16(a0, BA[q][1], accL[q]);
          accL[q] = MFMA16(a1, BA[q][0], accL[q]);
        }
      } else {
#pragma unroll
        for (int q = 0; q < 4; ++q) {
          BA[q][0] = *(const f16x8*)(pBp[q][0] + (size_t)ksn * 512);
          BA[q][1] = *(const f16x8*)(pBp[q][1] + (size_t)ksn * 512);
        }
#pragma unroll
        for (int q = 0; q < 4; ++q) {
          accH[q] = MFMA16(a0, BB[q][0], accH[q]);
          accL[q] = MFMA16(a0, BB[q][1], accL[q]);
          accL[q] = MFMA16(a1, BB[q][0], accL[q]);
        }
      }
    }
  }

#pragma unroll
  for (int r = 0; r < 16; ++r) {
    float bs = accH[0][r] + accL[0][r] * INV2048 - hnv[0];
    int   bj = (jg * 4 + 0) * 32 + lo;
#pragma unroll
    for (int q = 1; q < 4; ++q) {
      const float s = accH[q][r] + accL[q][r] * INV2048 - hnv[q];
      const int   j = (jg * 4 + q) * 32 + lo;
      if (s > bs) { bs = s; bj = j; }
    }
#pragma unroll
    for (int d = 1; d < 32; d <<= 1) {
      const float os = __shfl_xor(bs, d, 64);
      const int   oj = __shfl_xor(bj, d, 64);
      if (os > bs || (os == bs && oj < bj)) { bs = os; bj = oj; }
    }
    if (lo == 0) {
      const int wloc = m * 32 + (r & 3) + 8 * (r >> 2) + 4 * hi;
      scs[jg][wloc] = bs; scj[jg][wloc] = bj;
    }
  }
  __syncthreads();
  if (tid < 64) {
    float bs = scs[0][tid]; int bj = scj[0][tid];
#pragma unroll
    for (int g = 1; g < 4; ++g) {
      const float s = scs[g][tid]; const int j = scj[g][tid];
      if (s > bs || (s == bs && j < bj)) { bs = s; bj = j; }
    }
    bestj[tid] = bj;
  }
  __syncthreads();
  {
    const int rr = tid >> 6;
    const int c4 = (tid & 63) * 4;
#pragma unroll
    for (int pass = 0; pass < 8; ++pass) {
      const int r = pass * 8 + rr;
      const int jb = bestj[r];
      const float4 v = *(const float4*)(cbk + (size_t)jb * EE + c4);
      *(float4*)(out + (size_t)(w0 + r) * EE + c4) = v;
    }
  }
}

// ================= fallback: R1 fused VALU kernel (known-good) =================
#define V 8
#define LAGS 4
#define WIN 64
#define STEP 16
#define CONV_OUT 16
#define WPB 16
#define TPB 256
#define NWORD 19
#define YSTRIDE 80
#define XSPAN 304
#define FOFF_YS   0
#define FOFF_XS   10240
#define FOFF_ES   10240
#define FOFF_SC   0
#define FOFF_SI   4096
#define FOFF_PS   8192
#define FOFF_PI   8448
#define FOFF_IW   8704
#define SMEM_FLOATS 14336

__device__ __forceinline__ float f4get(const float4& v, int i) {
  return i == 0 ? v.x : (i == 1 ? v.y : (i == 2 ? v.z : v.w));
}

__device__ __forceinline__ float conv_one(const float* xs, int p, const float4* cw, float cb0) {
  float a = cb0;
#pragma unroll
  for (int v = 0; v < V; ++v) {
    const float4 xv = *(const float4*)(xs + v * XSPAN + 4 * p);
    a = fmaf(xv.x, cw[v].x, a);
    a = fmaf(xv.y, cw[v].y, a);
    a = fmaf(xv.z, cw[v].z, a);
    a = fmaf(xv.w, cw[v].w, a);
  }
  return fmaxf(a, 0.0f);
}

__global__ __launch_bounds__(TPB, 2)
void tok_fused(const float* __restrict__ x, const float* __restrict__ conv_w,
               const float* __restrict__ conv_b, const float* __restrict__ lin_w,
               const float* __restrict__ lin_b, const float* __restrict__ cbk,
               float* __restrict__ out)
{
  __shared__ float smem[SMEM_FLOATS];
  float* ys = smem + FOFF_YS;
  float* xs = smem + FOFF_XS;
  float* es = smem + FOFF_ES;
  float* sc = smem + FOFF_SC;
  int*   si = (int*)(smem + FOFF_SI);
  float* ps = smem + FOFF_PS;
  int*   pi = (int*)(smem + FOFF_PI);
  int*   iw = (int*)(smem + FOFF_IW);
  const int tid = threadIdx.x;
  const int b   = blockIdx.x >> 5;
  const int t0  = (blockIdx.x & 31) * WPB;
  const float* xb = x + (size_t)b * V * SSN + (size_t)t0 * STEP;
#pragma unroll
  for (int v = 0; v < V; ++v)
    for (int j = tid; j < XSPAN; j += TPB)
      xs[v * XSPAN + j] = xb[(size_t)v * SSN + j];
  double accd[WPB];
#pragma unroll
  for (int w = 0; w < WPB; ++w) accd[w] = 0.0;
  for (int half = 0; half < 2; ++half) {
    __syncthreads();
    {
      const int ep  = half * 128 + (tid >> 1);
      const int row = ep & 127;
      float4 cw[V];
      const float4* cwp = (const float4*)(conv_w + (size_t)ep * (V * LAGS));
#pragma unroll
      for (int v = 0; v < V; ++v) cw[v] = cwp[v];
      const float cb0 = conv_b[ep];
      const int c0 = (tid & 1) ? 10 : 0;
      const int c1 = (tid & 1) ? NWORD : 10;
      for (int c = c0; c < c1; ++c) {
        const int p = 4 * c;
        float r0 = conv_one(xs, p + 0, cw, cb0);
        float r1 = conv_one(xs, p + 1, cw, cb0);
        float r2 = conv_one(xs, p + 2, cw, cb0);
        float r3 = conv_one(xs, p + 3, cw, cb0);
        *(float4*)(ys + row * YSTRIDE + 4 * c) = make_float4(r0, r1, r2, r3);
      }
    }
    __syncthreads();
    const float* lwbase = lin_w + (size_t)tid * (EE * CONV_OUT) + half * (128 * CONV_OUT);
    float4 nA, nB, nC, nD;
    {
      const float4* p4 = (const float4*)(lwbase);
      nA = p4[0]; nB = p4[1]; nC = p4[2]; nD = p4[3];
    }
    for (int er = 0; er < 128; ++er) {
      const float4 lA = nA, lB = nB, lC = nC, lD = nD;
      const int ern = (er + 1) & 127;
      {
        const float4* p4 = (const float4*)(lwbase + ern * CONV_OUT);
        nA = p4[0]; nB = p4[1]; nC = p4[2]; nD = p4[3];
      }
      float4 yr[NWORD];
      const float4* yp = (const float4*)(ys + er * YSTRIDE);
#pragma unroll
      for (int q = 0; q < NWORD; ++q) yr[q] = yp[q];
      float it[WPB];
#pragma unroll
      for (int w = 0; w < WPB; ++w) it[w] = 0.0f;
#pragma unroll
      for (int o = 0; o < CONV_OUT; ++o) {
        const float lw_o = f4get(o < 4 ? lA : (o < 8 ? lB : (o < 12 ? lC : lD)), o & 3);
#pragma unroll
        for (int w = 0; w < WPB; ++w) {
          const int p = 4 * w + o;
          it[w] = fmaf(lw_o, f4get(yr[p >> 2], p & 3), it[w]);
        }
      }
#pragma unroll
      for (int w = 0; w < WPB; ++w) accd[w] += (double)it[w];
    }
  }
#pragma unroll
  for (int w = 0; w < WPB; ++w)
    es[w * EE + tid] = (float)accd[w] + lin_b[tid];
  __syncthreads();
  float s_best[WPB];
  int   i_best[WPB];
#pragma unroll
  for (int jj = 0; jj < 2; ++jj) {
    const int j = tid + jj * 256;
    const float4* cbp = (const float4*)(cbk + (size_t)j * EE);
    double sdd[WPB];
    float  sd32[WPB];
#pragma unroll
    for (int w = 0; w < WPB; ++w) { sdd[w] = 0.0; sd32[w] = 0.f; }
    double ndd = 0.0;
    float  nd32 = 0.f;
    float4 c4n = cbp[0];
    for (int i16 = 0; i16 < 4; ++i16) {
      for (int i4i = 0; i4i < 16; ++i4i) {
        const int i4 = i16 * 16 + i4i;
        const float4 c4 = c4n;
        c4n = cbp[(i4 + 1 <= 63) ? (i4 + 1) : 63];
        nd32 = fmaf(c4.x, c4.x, nd32);
        nd32 = fmaf(c4.y, c4.y, nd32);
        nd32 = fmaf(c4.z, c4.z, nd32);
        nd32 = fmaf(c4.w, c4.w, nd32);
#pragma unroll
        for (int w = 0; w < WPB; ++w) {
          const float4 e4 = *(const float4*)(es + w * EE + i4 * 4);
          sd32[w] = fmaf(c4.x, e4.x, sd32[w]);
          sd32[w] = fmaf(c4.y, e4.y, sd32[w]);
          sd32[w] = fmaf(c4.z, e4.z, sd32[w]);
          sd32[w] = fmaf(c4.w, e4.w, sd32[w]);
        }
      }
#pragma unroll
      for (int w = 0; w < WPB; ++w) { sdd[w] += (double)sd32[w]; sd32[w] = 0.f; }
      ndd += (double)nd32; nd32 = 0.f;
    }
#pragma unroll
    for (int w = 0; w < WPB; ++w) {
      const float s = (float)(sdd[w] - 0.5 * ndd);
      if (jj == 0) { s_best[w] = s; i_best[w] = j; }
      else if (s > s_best[w]) { s_best[w] = s; i_best[w] = j; }
    }
  }
#pragma unroll
  for (int w = 0; w < WPB; ++w) {
    sc[w * EE + tid] = s_best[w];
    si[w * EE + tid] = i_best[w];
  }
  __syncthreads();
  {
    const int w = tid >> 4, seg = tid & 15;
    float mm = -INFINITY; int mi = 0x7fffffff;
    for (int t = seg * 16; t < seg * 16 + 16; ++t) {
      const float s = sc[w * EE + t];
      const int   jx = si[w * EE + t];
      if (s > mm || (s == mm && jx < mi)) { mm = s; mi = jx; }
    }
    ps[w * 16 + seg] = mm; pi[w * 16 + seg] = mi;
  }
  __syncthreads();
  if (tid < WPB) {
    const int w = tid;
    float mm = -INFINITY; int mi = 0x7fffffff;
    for (int t = 0; t < 16; ++t) {
      const float s = ps[w * 16 + t];
      const int   jx = pi[w * 16 + t];
      if (s > mm || (s == mm && jx < mi)) { mm = s; mi = jx; }
    }
    iw[w] = mi;
  }
  __syncthreads();
  const size_t outb = ((size_t)b * TTOT + t0) * EE;
#pragma unroll
  for (int w = 0; w < WPB; ++w)
    out[outb + (size_t)w * EE + tid] = cbk[(size_t)iw[w] * EE + tid];
}

// ================= launch =================
extern "C" void kernel_launch(void* const* d_in, const int* in_sizes, int n_in,
                              void* d_out, int out_size, void* d_ws, size_t ws_size,
                              hipStream_t stream) {
  const float* x      = (const float*)d_in[0];
  const float* conv_w = (const float*)d_in[1];
  const float* conv_b = (const float*)d_in[2];
  const float* lin_w  = (const float*)d_in[3];
  const float* lin_b  = (const float*)d_in[4];
  const float* cbk    = (const float*)d_in[5];
  float* out = (float*)d_out;

  if (ws_size < WS_NEED) {
    tok_fused<<<dim3(32 * 32), dim3(TPB), 0, stream>>>(x, conv_w, conv_b, lin_w, lin_b, cbk, out);
    return;
  }
  char* ws = (char*)d_ws;
  f16*   y0   = (f16*)(ws + OFF_Y0);
  f16*   y1   = (f16*)(ws + OFF_Y1);
  f16*   lwp0 = (f16*)(ws + OFF_LW0);
  f16*   lwp1 = (f16*)(ws + OFF_LW1);
  f16*   cbp0 = (f16*)(ws + OFF_CB0);
  f16*   cbp1 = (f16*)(ws + OFF_CB1);
  float* hn   = (float*)(ws + OFF_HN);

  k01<<<848, 256, 0, stream>>>(lin_w, cbk, lwp0, lwp1, cbp0, cbp1, hn,
                               x, conv_w, conv_b, y0, y1);

  if (ws_size >= WS_NEED2) {
    float* pacc0 = (float*)(ws + OFF_E0);
    float* pacc1 = (float*)(ws + OFF_P1);
    k2ps<<<512, 256, 0, stream>>>(y0, y1, lwp0, lwp1, pacc0, pacc1);
    k3s<<<256, 512, 0, stream>>>(pacc0, pacc1, lin_b, cbp0, cbp1, hn, cbk, out);
  } else {
    f16* e0 = (f16*)(ws + OFF_E0);
    f16* e1 = (f16*)(ws + OFF_E1);
    k2_linear<<<256, 512, 0, stream>>>(y0, y1, lwp0, lwp1, lin_b, e0, e1);
    k3_old<<<256, 512, 0, stream>>>(e0, e1, cbp0, cbp1, hn, cbk, out);
  }
}